// Round 11
// baseline (9767.352 us; speedup 1.0000x reference)
//
#include <hip/hip_runtime.h>

typedef unsigned int u32;
typedef unsigned long long u64;
typedef unsigned short u16;
typedef __attribute__((ext_vector_type(8))) short short8;
typedef __attribute__((ext_vector_type(4))) float f32x4;

#define MFMA(a,b,c) __builtin_amdgcn_mfma_f32_16x16x32_bf16((a),(b),(c),0,0,0)
// Agent-scope (LLC) primitives — proven R3/R10 path.
#define ALOAD64(p)    __hip_atomic_load((p), __ATOMIC_RELAXED, __HIP_MEMORY_SCOPE_AGENT)
#define ALOAD32(p)    __hip_atomic_load((p), __ATOMIC_RELAXED, __HIP_MEMORY_SCOPE_AGENT)
#define ASTORE32(p,v) __hip_atomic_store((p),(v), __ATOMIC_RELAXED, __HIP_MEMORY_SCOPE_AGENT)

__device__ __forceinline__ float bf2f(u32 b){ union{u32 u; float f;} v; v.u = b<<16; return v.f; }
__device__ __forceinline__ u16 f2bf(float f){ union{float f; u32 u;} v; v.f = f; u32 u = v.u;
  return (u16)((u + 0x7fffu + ((u>>16)&1u)) >> 16); }
__device__ __forceinline__ u32 pack_f(float v){
  u16 hi = f2bf(v); u16 lo = f2bf(v - bf2f(hi)); return (u32)hi | ((u32)lo<<16); }

__device__ __forceinline__ void unpack8(uint4 a, uint4 b, short8& hi, short8& lo){
  u32 w[8] = {a.x,a.y,a.z,a.w,b.x,b.y,b.z,b.w};
#pragma unroll
  for (int j=0;j<8;++j){ hi[j] = (short)(w[j] & 0xffffu); lo[j] = (short)(w[j] >> 16); }
}
// 2 u64 = 4 u32 = 8 consecutive bf16 (hi-only h plane)
__device__ __forceinline__ void unpackh(u64 q0, u64 q1, short8& hi){
  u32 w[4] = {(u32)q0,(u32)(q0>>32),(u32)q1,(u32)(q1>>32)};
#pragma unroll
  for (int i=0;i<4;++i){ hi[2*i] = (short)(w[i] & 0xffffu); hi[2*i+1] = (short)(w[i] >> 16); }
}

// ---------------- workspace layout (bytes) ----------------
constexpr size_t OFF_Y    = 0;            // u32[1000][32][256]; reused as out2 [250][32][1024]
constexpr size_t OFF_SUB  = 32768000;     // u32[250][32][1024]
constexpr size_t OFF_W0IH = 65536000;     // L0 weight image hi: 128*30720 u16 = 7,864,320 B
constexpr size_t OFF_W0IL = 73400320;     // L0 weight image lo
constexpr size_t OFF_W1XH = 81264640;     // L1 compact blobs (R3 builder)
constexpr size_t OFF_W1XL = 87556096;
constexpr size_t OFF_W1HH = 93847552;
constexpr size_t OFF_W1HL = 100139008;
constexpr size_t OFF_HB0  = 106430464;    // bf16-hi plane u32[2][32][512] = 131072 B (in 262144 slot)
constexpr size_t OFF_HB1  = 106692608;
constexpr size_t OFF_FL0  = 106954752;    // int[256] pad 1KB
constexpr size_t OFF_FL1  = 106955776;
constexpr size_t WS_NEED  = 106956800;

// ---------------- L1 weight fragment builder (compact 12-col; R3-proven) ----------------
// blob: [wg=256][kq=8][kt=K/256][kseg=4][c=12][j=8] u16
// k = kq*(K/8) + kt*32 + kseg*8 + j ; col = (c>>2)*1024 + wg*4 + (c&3)
__global__ void build_frags(const float* __restrict__ W, u16* __restrict__ fhi,
                            u16* __restrict__ flo, int K){
  const int KT = K >> 8;
  size_t total = (size_t)K * 12 * 256;
  for (size_t i = (size_t)blockIdx.x*blockDim.x + threadIdx.x; i < total;
       i += (size_t)gridDim.x*blockDim.x){
    int j = (int)(i & 7); size_t r = i >> 3;
    int c = (int)(r % 12); r /= 12;
    int kseg = (int)(r & 3); r >>= 2;
    int kt = (int)(r % KT); r /= KT;
    int kq = (int)(r & 7); r >>= 3;
    int wg = (int)r;
    int k = kq*(K>>3) + kt*32 + kseg*8 + j;
    int col = (c>>2)*1024 + wg*4 + (c&3);
    float v = W[(size_t)k*3072 + col];
    u16 hi = f2bf(v);
    u16 lo = f2bf(v - bf2f(hi));
    fhi[i] = hi; flo[i] = lo;
  }
}

// ---------------- L0 weight image builder (8 units/WG, 128 WGs) — R7/R8-verified math ----------------
// Per-WG u16 image (30720 elems/plane), regions (element offsets):
//   [0,4096)      ZRX : 8 blocks of 512; k=blk*32+kseg*8+j (<256);  [Wxz8|Wxr8]
//   [4096,20480)  ZRH : 32 blocks;       k=blk*32+kseg*8+j (<1024); [Whz8|Whr8]
//   [20480,24576) HHF : 8 blocks;        k (<256);                  [Wxh8|Whh8]
//   [24576,30720) HHC : 24 blocks*256;   k=256+blk*32+kseg*8+j;     [Whh8] (8 cols)
__global__ void build_w0img(const float* __restrict__ w0x, const float* __restrict__ w0h,
                            u16* __restrict__ imgH, u16* __restrict__ imgL){
  for (size_t i = (size_t)blockIdx.x*blockDim.x + threadIdx.x; i < 128ull*30720ull;
       i += (size_t)gridDim.x*blockDim.x){
    int wg = (int)(i / 30720), e = (int)(i % 30720);
    int k, col; const float* src;
    if (e < 4096){
      int blk=e>>9, r=e&511, kseg=r>>7, c=(r>>3)&15, j=r&7;
      k = blk*32 + kseg*8 + j;
      col = (c<8) ? (wg*8+c) : (1024 + wg*8 + c-8); src = w0x;
    } else if (e < 20480){
      int e2=e-4096, blk=e2>>9, r=e2&511, kseg=r>>7, c=(r>>3)&15, j=r&7;
      k = blk*32 + kseg*8 + j;
      col = (c<8) ? (wg*8+c) : (1024 + wg*8 + c-8); src = w0h;
    } else if (e < 24576){
      int e2=e-20480, blk=e2>>9, r=e2&511, kseg=r>>7, c=(r>>3)&15, j=r&7;
      k = blk*32 + kseg*8 + j;
      if (c < 8){ col = 2048 + wg*8 + c;     src = w0x; }
      else      { col = 2048 + wg*8 + c - 8; src = w0h; }
    } else {
      int e2=e-24576, blk=e2>>8, r=e2&255, kseg=r>>6, c=(r>>3)&7, j=r&7;
      k = 256 + blk*32 + kseg*8 + j;
      col = 2048 + wg*8 + c; src = w0h;
    }
    float v = src[(size_t)k*3072 + col];
    u16 hi = f2bf(v);
    imgH[i] = hi; imgL[i] = f2bf(v - bf2f(hi));
  }
}

// ---------------- init h0 + flags (h planes = bf16-hi pairs packed in u32) ----------------
__global__ void init_state(const float* __restrict__ h0, u32* hb0, u32* hb1,
                           int* f0, int* f1){
  int i = blockIdx.x*blockDim.x + threadIdx.x;
  if (i < 256){ f0[i]=0; f1[i]=0; }
  if (i < 16384){               // slot 0: [32][512] u32 = pairs of units
    int p = i & 511;
    u32 v = (u32)f2bf(h0[2*p]) | ((u32)f2bf(h0[2*p+1]) << 16);
    hb0[i] = v;
    hb1[i] = 0u;
  }
}

// ---------------- conv + relu + pack ----------------
__global__ void conv_pack(const float* __restrict__ x, const float* __restrict__ cw,
                          u32* __restrict__ yp){
  for (size_t i = (size_t)blockIdx.x*blockDim.x + threadIdx.x; i < 8192000ull;
       i += (size_t)gridDim.x*blockDim.x){
    int f = (int)(i & 255); int b = (int)((i>>8)&31); int t = (int)(i>>13);
    const float* xb = x + ((size_t)b*1000 + t)*256 + f;
    float acc = xb[0]*cw[256+f];
    if (t > 0)   acc += xb[-256]*cw[f];
    if (t < 999) acc += xb[256]*cw[512+f];
    acc = fmaxf(acc, 0.0f);
    yp[i] = pack_f(acc);
  }
}

// ---------------- L0 persistent GRU: 128 WGs x 1024 thr, 8 units/WG ----------------
// STAGING FIX vs R7/R8: the plane copies were HALF-sized (u64 count = elems/8
// instead of elems/4) -> half of ZRH and all HHF were uninitialized LDS, which
// fully explains absmax~0.5. Correct counts: hi 24576 elems = 6144 u64,
// lo 20480 elems = 5120 u64.
// h plane: bf16-hi only (R10-verified numerics). Broadcast = 128 WGs x 64 KB
// = 8 MB/step agent-LLC reads (2x less than R10).
__global__ __launch_bounds__(1024, 1)
void gru8_persist(const u32* __restrict__ xin,
                  const u16* __restrict__ imgH, const u16* __restrict__ imgL,
                  const float* __restrict__ bias,
                  u32* hbuf, int* flags, u32* out_pack)
{
  __shared__ u16 WIMG[45056];        // hi[0,24576) + lo{ZRH,HHF}[24576,45056) = 90,112 B
  __shared__ float exch[256*33];     // 33,792 B
  __shared__ float harr[256];        // 1,024 B    -> total 124,928 B

  const int tid  = threadIdx.x;
  const int wg   = blockIdx.x;
  const int lane = tid & 63;
  const int wave = tid >> 6;
  const int m    = wave & 1;
  const int kq   = wave >> 1;
  const int lo16 = lane & 15, hi16 = lane >> 4;
  const int lane_off = hi16*128 + lo16*8;

  { // stage: hi plane 24576 elems (6144 u64); lo plane = img elems [4096,24576) (5120 u64)
    const u64* sH = (const u64*)(imgH + (size_t)wg*30720);
    const u64* sL = (const u64*)(imgL + (size_t)wg*30720 + 4096);
    u64* dH = (u64*)WIMG;
    u64* dL = (u64*)(WIMG + 24576);
    for (int i = tid; i < 6144; i += 1024) dH[i] = sH[i];
    for (int i = tid; i < 5120; i += 1024) dL[i] = sL[i];
    if (tid < 256){
      u16 hv = ((const u16*)hbuf)[(tid>>3)*1024 + wg*8 + (tid&7)];   // slot 0
      harr[tid] = bf2f((u32)hv);
    }
  }
  __syncthreads();

  // fragment pointers. LDS lo(img elem e) = WIMG[e + 20480] for e in [4096,24576).
  const u16* zrx_h  = &WIMG[kq*512 + lane_off];
  const u16* zrxg_l = imgL + (size_t)wg*30720 + kq*512 + lane_off;          // global
  const u16* zrh_h  = &WIMG[4096 + kq*2048 + lane_off];                     // +kt*512; lo=+20480
  const u16* hhx_h  = &WIMG[20480 + kq*512 + lane_off];                     // lo=+20480
  const bool hhLds  = (kq < 2);
  const u16* hhb_h; const u16* hhb_l; int hhstride;
  if (hhLds){
    hhb_h = &WIMG[20480 + kq*2048 + lane_off]; hhb_l = hhb_h + 20480; hhstride = 512;
  } else {
    size_t go = (size_t)wg*30720 + 24576 + (size_t)(kq-2)*1024 + hi16*64
              + ((lo16 >= 8) ? (lo16-8)*8 : 0);   // lo16<8 lanes: valid addr, result discarded
    hhb_h = imgH + go; hhb_l = imgL + go; hhstride = 256;
  }

  const int gs = tid >> 3, gu = tid & 7, eu = wg*8 + gu;
  const float zb  = bias[eu]        + bias[3072 + eu];
  const float rbv = bias[1024 + eu] + bias[4096 + eu];
  const float hxb = bias[2048 + eu];
  const float hrb = bias[5120 + eu];

  for (int t = 0; t < 1000; ++t) {
    const int cur = t & 1, nxt = cur ^ 1;
    f32x4 aZR = (f32x4){0.f,0.f,0.f,0.f};
    f32x4 aHX = (f32x4){0.f,0.f,0.f,0.f};
    f32x4 aHR = (f32x4){0.f,0.f,0.f,0.f};
    { // x-pass (h-independent; overlaps laggard flag propagation)
      const u32* xr = xin + ((size_t)t*32 + 16*m + lo16)*256 + kq*32 + hi16*8;
      uint4 a0 = *(const uint4*)xr;
      uint4 a1 = *(const uint4*)(xr + 4);
      short8 ahi, alo; unpack8(a0, a1, ahi, alo);
      short8 b1h = *(const short8*)zrx_h, b1l = *(const short8*)zrxg_l;
      short8 b2h = *(const short8*)hhx_h, b2l = *(const short8*)(hhx_h + 20480);
      aZR = MFMA(ahi,b1h,aZR); aZR = MFMA(alo,b1h,aZR); aZR = MFMA(ahi,b1l,aZR);
      aHX = MFMA(ahi,b2h,aHX); aHX = MFMA(alo,b2h,aHX); aHX = MFMA(ahi,b2l,aHX);
    }
    if (t > 0) { // wave0 polls 128 flags (2 lines); others park at barrier
      if (wave == 0) {
        int f0, f1;
        do { f0 = ALOAD32(flags + lane); f1 = ALOAD32(flags + 64 + lane); }
        while (!__all(f0 >= t && f1 >= t));
      }
      __syncthreads();
    }
    { // h-pass: bf16-hi agent loads from LLC (half bytes, 2 MFMAs per tile-pair)
      const u32* hrow = hbuf + cur*16384 + (16*m + lo16)*512 + kq*64 + hi16*4;
      u64 q[8];
#pragma unroll
      for (int kt = 0; kt < 4; ++kt){
        const u64* hq = (const u64*)(hrow + kt*16);
        q[kt*2]   = ALOAD64(hq);
        q[kt*2+1] = ALOAD64(hq + 1);
      }
#pragma unroll
      for (int kt = 0; kt < 4; ++kt){
        short8 ahi; unpackh(q[kt*2], q[kt*2+1], ahi);
        short8 b1h = *(const short8*)(zrh_h + kt*512);
        short8 b1l = *(const short8*)(zrh_h + kt*512 + 20480);
        short8 b2h = *(const short8*)(hhb_h + kt*hhstride);
        short8 b2l = *(const short8*)(hhb_l + kt*hhstride);
        aZR = MFMA(ahi,b1h,aZR); aZR = MFMA(ahi,b1l,aZR);
        aHR = MFMA(ahi,b2h,aHR); aHR = MFMA(ahi,b2l,aHR);
      }
    }
    { // exchange: cols 0-15 = z|r (aZR), 16-23 = xh (aHX, lo16<8), 24-31 = rh (aHR, lo16>=8)
      const int bb = 16*m + hi16*4;
#pragma unroll
      for (int r4 = 0; r4 < 4; ++r4){
        exch[(kq*32 + bb + r4)*33 + lo16]      = aZR[r4];
        exch[(kq*32 + bb + r4)*33 + 16 + lo16] = (lo16 < 8) ? aHX[r4] : aHR[r4];
      }
    }
    __syncthreads();
    if (tid < 256) { // gates: one (sample, unit) per thread
      float zp=0.f, rp=0.f, xh=0.f, rh=0.f;
#pragma unroll
      for (int k8 = 0; k8 < 8; ++k8){
        const float* e = &exch[(k8*32 + gs)*33];
        zp += e[gu]; rp += e[8+gu]; xh += e[16+gu]; rh += e[24+gu];
      }
      float z = 1.f/(1.f + __expf(-(zp + zb)));
      float r = 1.f/(1.f + __expf(-(rp + rbv)));
      float pre = xh + hxb + r*(rh + hrb);
      float ex = __expf(-2.f*fabsf(pre));
      float th = (1.f - ex)/(1.f + ex);
      float hh = copysignf(th, pre);
      float hn = z*harr[tid] + (1.f - z)*hh;
      harr[tid] = hn;
      u32 pk = pack_f(hn);
      if ((t & 3) == 0)
        out_pack[((size_t)(t>>2)*32 + gs)*1024 + eu] = pk;   // packed {hi,lo} for L1
      // h broadcast: bf16-hi only, two adjacent units packed per u32
      int pk16 = (int)(pk & 0xffffu);
      int prt  = __shfl_xor(pk16, 1);               // partner unit (gu^1), same sample
      if ((tid & 1) == 0) {
        u32 pair = (u32)pk16 | ((u32)prt << 16);    // low = even unit
        ASTORE32(hbuf + nxt*16384 + gs*512 + wg*4 + (gu>>1), pair);
      }
    }
    asm volatile("s_waitcnt vmcnt(0)" ::: "memory");   // stores acked at LLC
    __syncthreads();
    if (tid == 0)
      ASTORE32(flags + wg, t+1);
  }
}

// ---------------- L1 persistent GRU (R10-verified: 256 WGs, 4 units, bf16-hi h) ----------------
__global__ __launch_bounds__(1024, 1)
void gru_persist1(const u32* __restrict__ xin,
                  const u16* __restrict__ wxf_hi, const u16* __restrict__ wxf_lo,
                  const u16* __restrict__ whf_hi, const u16* __restrict__ whf_lo,
                  const float* __restrict__ bias,
                  u32* hbuf, int* flags, u32* out_pack)
{
  constexpr int T   = 250;
  constexpr int KX  = 1024;
  constexpr int KTX = 4;
  __shared__ u16 WxHi[8*KTX*512], WxLo[8*KTX*512];
  __shared__ u16 WhHi[8*4*512],  WhLo[8*4*512];
  __shared__ float exch[8*32*18];
  __shared__ float harr[128];

  const int tid  = threadIdx.x;
  const int wg   = blockIdx.x;
  const int lane = tid & 63;
  const int wave = tid >> 6;
  const int m    = wave & 1;
  const int kq   = wave >> 1;
  const int u0   = wg * 4;
  const int lo16 = lane & 15, hi16 = lane >> 4;
  const int lane_off = hi16*128 + lo16*8;

  { // zero weight LDS (pad cols)
    for (int i = tid; i < 8*KTX*512/4; i += 1024){ ((u64*)WxHi)[i]=0; ((u64*)WxLo)[i]=0; }
    for (int i = tid; i < 8*4*512/4;  i += 1024){ ((u64*)WhHi)[i]=0; ((u64*)WhLo)[i]=0; }
  }
  __syncthreads();
  { // scatter compact blobs into padded LDS tiles (R3-proven)
    const u16* bx_hi = wxf_hi + (size_t)wg*KX*12;
    const u16* bx_lo = wxf_lo + (size_t)wg*KX*12;
    const u16* bh_hi = whf_hi + (size_t)wg*1024*12;
    const u16* bh_lo = whf_lo + (size_t)wg*1024*12;
    for (int i = tid; i < 8*KTX*48; i += 1024){
      int c = i % 12; int r = i/12; int kseg = r & 3; r >>= 2;
      int kt = r % KTX; int kqq = r / KTX;
      int ldsoff = ((kqq*KTX+kt)*4+kseg)*128 + c*8;            // [z r xh 0]
      *(short8*)&WxHi[ldsoff] = *(const short8*)&bx_hi[(size_t)i*8];
      *(short8*)&WxLo[ldsoff] = *(const short8*)&bx_lo[(size_t)i*8];
    }
    for (int i = tid; i < 8*4*48; i += 1024){
      int c = i % 12; int r = i/12; int kseg = r & 3; r >>= 2;
      int kt = r & 3; int kqq = r >> 2;
      int cm = (c < 8) ? c : (c + 4);                          // [z r 0 rh]
      int ldsoff = ((kqq*4+kt)*4+kseg)*128 + cm*8;
      *(short8*)&WhHi[ldsoff] = *(const short8*)&bh_hi[(size_t)i*8];
      *(short8*)&WhLo[ldsoff] = *(const short8*)&bh_lo[(size_t)i*8];
    }
    if (tid < 128){   // local fp32 h state from slot-0 bf16 plane
      u16 hv = ((const u16*)hbuf)[(tid>>2)*1024 + u0 + (tid&3)];
      harr[tid] = bf2f((u32)hv);
    }
  }
  __syncthreads();

  const int eb = tid >> 2, eu_l = tid & 3, eu = u0 + eu_l;
  const float zb  = bias[eu]        + bias[3072 + eu];
  const float rbv = bias[1024 + eu] + bias[4096 + eu];
  const float hxb = bias[2048 + eu];
  const float hrb = bias[5120 + eu];

  for (int t = 0; t < T; ++t) {
    const int cur = t & 1, nxt = cur ^ 1;
    f32x4 xacc = (f32x4){0.f,0.f,0.f,0.f};
    f32x4 racc = (f32x4){0.f,0.f,0.f,0.f};
    { // xproj (h-independent)
      const u32* xrow = xin + ((size_t)t*32 + 16*m + lo16)*KX + kq*(KX>>3) + hi16*8;
#pragma unroll
      for (int kt = 0; kt < KTX; ++kt) {
        uint4 a0 = *(const uint4*)(xrow + kt*32);
        uint4 a1 = *(const uint4*)(xrow + kt*32 + 4);
        short8 ahi, alo; unpack8(a0, a1, ahi, alo);
        short8 bhi = *(const short8*)&WxHi[(kq*KTX+kt)*512 + lane_off];
        short8 blo = *(const short8*)&WxLo[(kq*KTX+kt)*512 + lane_off];
        xacc = MFMA(ahi, bhi, xacc);
        xacc = MFMA(alo, bhi, xacc);
        xacc = MFMA(ahi, blo, xacc);
      }
    }
    if (t > 0) {
      if (wave == 0) {
        int f0,f1,f2,f3;
        do {
          f0 = ALOAD32(flags + lane);       f1 = ALOAD32(flags + 64 + lane);
          f2 = ALOAD32(flags + 128 + lane); f3 = ALOAD32(flags + 192 + lane);
        } while (!__all(f0 >= t && f1 >= t && f2 >= t && f3 >= t));
      }
      __syncthreads();
    }
    { // recurrent: bf16-hi h slice
      const u32* hrow = hbuf + cur*16384 + (16*m + lo16)*512 + kq*64 + hi16*4;
      u64 q[8];
#pragma unroll
      for (int kt = 0; kt < 4; ++kt){
        const u64* hq = (const u64*)(hrow + kt*16);
        q[kt*2]   = ALOAD64(hq);
        q[kt*2+1] = ALOAD64(hq + 1);
      }
#pragma unroll
      for (int kt = 0; kt < 4; ++kt) {
        short8 ahi; unpackh(q[kt*2], q[kt*2+1], ahi);
        short8 bhi = *(const short8*)&WhHi[(kq*4+kt)*512 + lane_off];
        short8 blo = *(const short8*)&WhLo[(kq*4+kt)*512 + lane_off];
        racc = MFMA(ahi, bhi, racc);
        racc = MFMA(ahi, blo, racc);
      }
    }
    {
      const int bb = 16*m + hi16*4;
#pragma unroll
      for (int r4 = 0; r4 < 4; ++r4)
        exch[(kq*32 + bb + r4)*18 + lo16] = xacc[r4] + racc[r4];
    }
    __syncthreads();
    if (tid < 128) {
      float zp=0.f, rp=0.f, xh=0.f, rh=0.f;
#pragma unroll
      for (int qd = 0; qd < 8; ++qd) {
        const float* e = &exch[(qd*32 + eb)*18];
        zp += e[eu_l];
        rp += e[4 + eu_l];
        xh += e[8 + eu_l];
        rh += e[12 + eu_l];
      }
      float z = 1.f/(1.f + __expf(-(zp + zb)));
      float r = 1.f/(1.f + __expf(-(rp + rbv)));
      float pre = xh + hxb + r*(rh + hrb);
      float ex = __expf(-2.f*fabsf(pre));
      float th = (1.f - ex)/(1.f + ex);
      float hh = copysignf(th, pre);
      float hn = z*harr[tid] + (1.f - z)*hh;
      harr[tid] = hn;
      u32 pk = pack_f(hn);
      out_pack[((size_t)t*32 + eb)*1024 + u0 + eu_l] = pk;
      int pk16 = (int)(pk & 0xffffu);
      int prt  = __shfl_xor(pk16, 1);
      if ((tid & 1) == 0) {
        u32 pair = (u32)pk16 | ((u32)prt << 16);
        ASTORE32(hbuf + nxt*16384 + eb*512 + wg*2 + (eu_l>>1), pair);
      }
    }
    asm volatile("s_waitcnt vmcnt(0)" ::: "memory");
    __syncthreads();
    if (tid == 0)
      ASTORE32(flags + wg, t+1);
  }
}

// ---------------- final dense head ----------------
__global__ __launch_bounds__(256, 1)
void dense_k(const u32* __restrict__ h2, const float* __restrict__ W,
             const float* __restrict__ bias, float* __restrict__ out){
  __shared__ float rows[32*1025];
  const int ts = blockIdx.x;
  const u32* src = h2 + (size_t)ts*32768;
  for (int i = threadIdx.x; i < 32768; i += 256){
    u32 p = src[i];
    rows[(i>>10)*1025 + (i&1023)] = bf2f(p & 0xffffu) + bf2f(p >> 16);
  }
  __syncthreads();
  const int b = threadIdx.x >> 3, cg = threadIdx.x & 7;
  float acc[6] = {0.f,0.f,0.f,0.f,0.f,0.f};
  for (int k = 0; k < 1024; ++k){
    float hv = rows[b*1025 + k];
    const float* wr = W + k*41;
#pragma unroll
    for (int j = 0; j < 6; ++j){ int c = cg + 8*j; if (c < 41) acc[j] += hv*wr[c]; }
  }
#pragma unroll
  for (int j = 0; j < 6; ++j){
    int c = cg + 8*j;
    if (c < 41) out[((size_t)b*250 + ts)*41 + c] = acc[j] + bias[c];
  }
}

// ---------------- launch ----------------
extern "C" void kernel_launch(void* const* d_in, const int* in_sizes, int n_in,
                              void* d_out, int out_size, void* d_ws, size_t ws_size,
                              hipStream_t stream) {
  const float* x      = (const float*)d_in[0];
  const float* conv_w = (const float*)d_in[1];
  const float* h0i    = (const float*)d_in[2];
  const float* w0x    = (const float*)d_in[3];
  const float* w0h    = (const float*)d_in[4];
  const float* b0     = (const float*)d_in[5];
  const float* w1x    = (const float*)d_in[6];
  const float* w1h    = (const float*)d_in[7];
  const float* b1     = (const float*)d_in[8];
  const float* dw     = (const float*)d_in[9];
  const float* db     = (const float*)d_in[10];
  float* outp = (float*)d_out;

  if (ws_size < WS_NEED) return;  // workspace too small: leave output poisoned

  char* ws = (char*)d_ws;
  u32* y_pack   = (u32*)(ws + OFF_Y);
  u32* out2     = (u32*)(ws + OFF_Y);      // reuse after y_pack is dead
  u32* sub_pack = (u32*)(ws + OFF_SUB);
  u16* w0iH = (u16*)(ws + OFF_W0IH); u16* w0iL = (u16*)(ws + OFF_W0IL);
  u16* w1x_hi = (u16*)(ws + OFF_W1XH); u16* w1x_lo = (u16*)(ws + OFF_W1XL);
  u16* w1h_hi = (u16*)(ws + OFF_W1HH); u16* w1h_lo = (u16*)(ws + OFF_W1HL);
  u32* hb0 = (u32*)(ws + OFF_HB0);
  u32* hb1 = (u32*)(ws + OFF_HB1);
  int* fl0 = (int*)(ws + OFF_FL0);
  int* fl1 = (int*)(ws + OFF_FL1);

  init_state<<<64, 512, 0, stream>>>(h0i, hb0, hb1, fl0, fl1);
  build_w0img<<<2048, 256, 0, stream>>>(w0x, w0h, w0iH, w0iL);
  build_frags<<<2048, 256, 0, stream>>>(w1x, w1x_hi, w1x_lo, 1024);
  build_frags<<<2048, 256, 0, stream>>>(w1h, w1h_hi, w1h_lo, 1024);
  conv_pack<<<4096, 256, 0, stream>>>(x, conv_w, y_pack);

  gru8_persist<<<128, 1024, 0, stream>>>(y_pack, w0iH, w0iL, b0, hb0, fl0, sub_pack);
  gru_persist1<<<256, 1024, 0, stream>>>(sub_pack, w1x_hi, w1x_lo, w1h_hi, w1h_lo,
                                         b1, hb1, fl1, out2);

  dense_k<<<250, 256, 0, stream>>>(out2, dw, db, outp);
}

// Round 12
// 6468.294 us; speedup vs baseline: 1.5100x; 1.5100x over previous
//
#include <hip/hip_runtime.h>

typedef unsigned int u32;
typedef unsigned long long u64;
typedef unsigned short u16;
typedef __attribute__((ext_vector_type(8))) short short8;
typedef __attribute__((ext_vector_type(4))) float f32x4;
typedef __attribute__((ext_vector_type(4))) unsigned int u32x4;

#define MFMA(a,b,c) __builtin_amdgcn_mfma_f32_16x16x32_bf16((a),(b),(c),0,0,0)
// Agent-scope (LLC) primitives — proven R3/R10 path.
#define ALOAD32(p)    __hip_atomic_load((p), __ATOMIC_RELAXED, __HIP_MEMORY_SCOPE_AGENT)
#define ASTORE32(p,v) __hip_atomic_store((p),(v), __ATOMIC_RELAXED, __HIP_MEMORY_SCOPE_AGENT)

__device__ __forceinline__ float bf2f(u32 b){ union{u32 u; float f;} v; v.u = b<<16; return v.f; }
__device__ __forceinline__ u16 f2bf(float f){ union{float f; u32 u;} v; v.f = f; u32 u = v.u;
  return (u16)((u + 0x7fffu + ((u>>16)&1u)) >> 16); }
__device__ __forceinline__ u32 pack_f(float v){
  u16 hi = f2bf(v); u16 lo = f2bf(v - bf2f(hi)); return (u32)hi | ((u32)lo<<16); }

__device__ __forceinline__ void unpack8(uint4 a, uint4 b, short8& hi, short8& lo){
  u32 w[8] = {a.x,a.y,a.z,a.w,b.x,b.y,b.z,b.w};
#pragma unroll
  for (int j=0;j<8;++j){ hi[j] = (short)(w[j] & 0xffffu); lo[j] = (short)(w[j] >> 16); }
}
// one u32x4 (16 B) = 8 consecutive bf16 of the hi-only h plane
__device__ __forceinline__ void unpackh4(u32x4 a, short8& hi){
#pragma unroll
  for (int i=0;i<4;++i){ hi[2*i] = (short)(a[i] & 0xffffu); hi[2*i+1] = (short)(a[i] >> 16); }
}

// ---------------- workspace layout (bytes) — identical to R10 ----------------
constexpr size_t OFF_Y    = 0;            // u32[1000][32][256]; reused as out2 [250][32][1024]
constexpr size_t OFF_SUB  = 32768000;     // u32[250][32][1024]
constexpr size_t OFF_W0XH = 65536000;
constexpr size_t OFF_W0XL = 67108864;
constexpr size_t OFF_W0HH = 68681728;
constexpr size_t OFF_W0HL = 74973184;
constexpr size_t OFF_W1XH = 81264640;
constexpr size_t OFF_W1XL = 87556096;
constexpr size_t OFF_W1HH = 93847552;
constexpr size_t OFF_W1HL = 100139008;
constexpr size_t OFF_HB0  = 106430464;    // bf16-hi plane u32[2][32][512] = 131072 B (in 262144 slot)
constexpr size_t OFF_HB1  = 106692608;
constexpr size_t OFF_FL0  = 106954752;    // int[256] pad 1KB
constexpr size_t OFF_FL1  = 106955776;
constexpr size_t WS_NEED  = 106956800;

// ---------------- weight fragment builder (compact 12-col; R3-proven) ----------------
// blob: [wg=256][kq=8][kt=K/256][kseg=4][c=12][j=8] u16
// k = kq*(K/8) + kt*32 + kseg*8 + j ; col = (c>>2)*1024 + wg*4 + (c&3)
__global__ void build_frags(const float* __restrict__ W, u16* __restrict__ fhi,
                            u16* __restrict__ flo, int K){
  const int KT = K >> 8;
  size_t total = (size_t)K * 12 * 256;
  for (size_t i = (size_t)blockIdx.x*blockDim.x + threadIdx.x; i < total;
       i += (size_t)gridDim.x*blockDim.x){
    int j = (int)(i & 7); size_t r = i >> 3;
    int c = (int)(r % 12); r /= 12;
    int kseg = (int)(r & 3); r >>= 2;
    int kt = (int)(r % KT); r /= KT;
    int kq = (int)(r & 7); r >>= 3;
    int wg = (int)r;
    int k = kq*(K>>3) + kt*32 + kseg*8 + j;
    int col = (c>>2)*1024 + wg*4 + (c&3);
    float v = W[(size_t)k*3072 + col];
    u16 hi = f2bf(v);
    u16 lo = f2bf(v - bf2f(hi));
    fhi[i] = hi; flo[i] = lo;
  }
}

// ---------------- init h0 + flags (h plane = bf16-hi pairs packed in u32) ----------------
__global__ void init_state(const float* __restrict__ h0, u32* hb0, u32* hb1,
                           int* f0, int* f1){
  int i = blockIdx.x*blockDim.x + threadIdx.x;
  if (i < 256){ f0[i]=0; f1[i]=0; }
  if (i < 16384){               // slot 0: [32][512] u32 = pairs of units
    int p = i & 511;
    u32 v = (u32)f2bf(h0[2*p]) | ((u32)f2bf(h0[2*p+1]) << 16);
    hb0[i] = v;
    hb1[i] = 0u;
  }
}

// ---------------- conv + relu + pack ----------------
__global__ void conv_pack(const float* __restrict__ x, const float* __restrict__ cw,
                          u32* __restrict__ yp){
  for (size_t i = (size_t)blockIdx.x*blockDim.x + threadIdx.x; i < 8192000ull;
       i += (size_t)gridDim.x*blockDim.x){
    int f = (int)(i & 255); int b = (int)((i>>8)&31); int t = (int)(i>>13);
    const float* xb = x + ((size_t)b*1000 + t)*256 + f;
    float acc = xb[0]*cw[256+f];
    if (t > 0)   acc += xb[-256]*cw[f];
    if (t < 999) acc += xb[256]*cw[512+f];
    acc = fmaxf(acc, 0.0f);
    yp[i] = pack_f(acc);
  }
}

// ---------------- persistent GRU layer (R10 + split-half release + dwordx4 h loads) ----------------
// 256 WGs x 1024 threads. WG owns 4 units. Weights fully LDS-resident.
// h plane: bf16-hi only (R10-verified numerics).
// Split-half: wave0 polls flags[0..127] (producers of units 0..511), wave1 polls
// flags[128..255]; each sets an LDS release word. Compute waves spin on the LDS
// word for their own K-half (kq<4 -> A, kq>=4 -> B) -- early half's h ingest+MFMA
// overlaps the late half's flag propagation. 2-slot safety: the exch barrier
// still joins all 16 waves (=> all 256 flags >= t) before any h(t+1) store.
template<int LAYER>
__global__ __launch_bounds__(1024, 1)
void gru_persist(const u32* __restrict__ xin,
                 const u16* __restrict__ wxf_hi, const u16* __restrict__ wxf_lo,
                 const u16* __restrict__ whf_hi, const u16* __restrict__ whf_lo,
                 const float* __restrict__ bias,
                 u32* hbuf, int* flags, u32* out_pack)
{
  constexpr int T   = (LAYER==0) ? 1000 : 250;
  constexpr int KX  = (LAYER==0) ? 256 : 1024;
  constexpr int KTX = KX >> 8;
  __shared__ u16 WxHi[8*KTX*512], WxLo[8*KTX*512];
  __shared__ u16 WhHi[8*4*512],  WhLo[8*4*512];
  __shared__ float exch[8*32*18];
  __shared__ float harr[128];
  __shared__ int hready[32];     // [0]=half A step, [16]=half B step (padded)

  const int tid  = threadIdx.x;
  const int wg   = blockIdx.x;
  const int lane = tid & 63;
  const int wave = tid >> 6;
  const int m    = wave & 1;
  const int kq   = wave >> 1;
  const int u0   = wg * 4;
  const int lo16 = lane & 15, hi16 = lane >> 4;
  const int lane_off = hi16*128 + lo16*8;
  const int hsel = (kq >= 4) ? 16 : 0;

  { // zero weight LDS (pad cols) + release words
    for (int i = tid; i < 8*KTX*512/4; i += 1024){ ((u64*)WxHi)[i]=0; ((u64*)WxLo)[i]=0; }
    for (int i = tid; i < 8*4*512/4;  i += 1024){ ((u64*)WhHi)[i]=0; ((u64*)WhLo)[i]=0; }
    if (tid < 32) hready[tid] = 0;
  }
  __syncthreads();
  { // scatter compact blobs into padded LDS tiles (identical to R3/R10)
    const u16* bx_hi = wxf_hi + (size_t)wg*KX*12;
    const u16* bx_lo = wxf_lo + (size_t)wg*KX*12;
    const u16* bh_hi = whf_hi + (size_t)wg*1024*12;
    const u16* bh_lo = whf_lo + (size_t)wg*1024*12;
    for (int i = tid; i < 8*KTX*48; i += 1024){
      int c = i % 12; int r = i/12; int kseg = r & 3; r >>= 2;
      int kt = r % KTX; int kqq = r / KTX;
      int ldsoff = ((kqq*KTX+kt)*4+kseg)*128 + c*8;            // [z r xh 0]
      *(short8*)&WxHi[ldsoff] = *(const short8*)&bx_hi[(size_t)i*8];
      *(short8*)&WxLo[ldsoff] = *(const short8*)&bx_lo[(size_t)i*8];
    }
    for (int i = tid; i < 8*4*48; i += 1024){
      int c = i % 12; int r = i/12; int kseg = r & 3; r >>= 2;
      int kt = r & 3; int kqq = r >> 2;
      int cm = (c < 8) ? c : (c + 4);                          // [z r 0 rh]
      int ldsoff = ((kqq*4+kt)*4+kseg)*128 + cm*8;
      *(short8*)&WhHi[ldsoff] = *(const short8*)&bh_hi[(size_t)i*8];
      *(short8*)&WhLo[ldsoff] = *(const short8*)&bh_lo[(size_t)i*8];
    }
    if (tid < 128){   // local fp32 h state from slot-0 bf16 plane
      u16 hv = ((const u16*)hbuf)[(tid>>2)*1024 + u0 + (tid&3)];
      harr[tid] = bf2f((u32)hv);
    }
  }
  __syncthreads();

  const int eb = tid >> 2, eu_l = tid & 3, eu = u0 + eu_l;
  const float zb  = bias[eu]        + bias[3072 + eu];
  const float rbv = bias[1024 + eu] + bias[4096 + eu];
  const float hxb = bias[2048 + eu];
  const float hrb = bias[5120 + eu];

  for (int t = 0; t < T; ++t) {
    const int cur = t & 1, nxt = cur ^ 1;
    f32x4 xacc = (f32x4){0.f,0.f,0.f,0.f};
    f32x4 racc = (f32x4){0.f,0.f,0.f,0.f};
    { // xproj (h-independent; overlaps laggard flag propagation) — unchanged R10
      const u32* xrow = xin + ((size_t)t*32 + 16*m + lo16)*KX + kq*(KX>>3) + hi16*8;
#pragma unroll
      for (int kt = 0; kt < KTX; ++kt) {
        uint4 a0 = *(const uint4*)(xrow + kt*32);
        uint4 a1 = *(const uint4*)(xrow + kt*32 + 4);
        short8 ahi, alo; unpack8(a0, a1, ahi, alo);
        short8 bhi = *(const short8*)&WxHi[(kq*KTX+kt)*512 + lane_off];
        short8 blo = *(const short8*)&WxLo[(kq*KTX+kt)*512 + lane_off];
        xacc = MFMA(ahi, bhi, xacc);
        xacc = MFMA(alo, bhi, xacc);
        xacc = MFMA(ahi, blo, xacc);
      }
    }
    // split-half wait: wave0 -> flags[0..127] -> hready[0]; wave1 -> flags[128..255]
    // -> hready[16]; every wave spins (LDS, no fabric traffic) on its own half.
    if (t > 0) {
      if (wave == 0) {
        int f0, f1;
        do { f0 = ALOAD32(flags + lane); f1 = ALOAD32(flags + 64 + lane); }
        while (!__all(f0 >= t && f1 >= t));
        asm volatile("" ::: "memory");
        if (lane == 0) ((volatile int*)hready)[0] = t;
      } else if (wave == 1) {
        int f2, f3;
        do { f2 = ALOAD32(flags + 128 + lane); f3 = ALOAD32(flags + 192 + lane); }
        while (!__all(f2 >= t && f3 >= t));
        asm volatile("" ::: "memory");
        if (lane == 0) ((volatile int*)hready)[16] = t;
      }
      while (((volatile int*)hready)[hsel] < t) { }
      asm volatile("" ::: "memory");   // pin h loads behind the release
    }
    { // recurrent: bf16-hi h slice; 4x dwordx4 LLC loads (16B/lane, line-perfect)
      const u32* hrow = hbuf + cur*16384 + (16*m + lo16)*512 + kq*64 + hi16*4;
      u32x4 qa, qb, qc, qd;
      asm volatile(
        "global_load_dwordx4 %0, %4, off sc0 sc1\n\t"
        "global_load_dwordx4 %1, %4, off offset:64 sc0 sc1\n\t"
        "global_load_dwordx4 %2, %4, off offset:128 sc0 sc1\n\t"
        "global_load_dwordx4 %3, %4, off offset:192 sc0 sc1\n\t"
        "s_waitcnt vmcnt(0)"
        : "=&v"(qa), "=&v"(qb), "=&v"(qc), "=&v"(qd)
        : "v"(hrow)
        : "memory");
      short8 ah0, ah1, ah2, ah3;
      unpackh4(qa, ah0); unpackh4(qb, ah1); unpackh4(qc, ah2); unpackh4(qd, ah3);
      {
        short8 bhi = *(const short8*)&WhHi[(kq*4+0)*512 + lane_off];
        short8 blo = *(const short8*)&WhLo[(kq*4+0)*512 + lane_off];
        racc = MFMA(ah0, bhi, racc); racc = MFMA(ah0, blo, racc);
      }
      {
        short8 bhi = *(const short8*)&WhHi[(kq*4+1)*512 + lane_off];
        short8 blo = *(const short8*)&WhLo[(kq*4+1)*512 + lane_off];
        racc = MFMA(ah1, bhi, racc); racc = MFMA(ah1, blo, racc);
      }
      {
        short8 bhi = *(const short8*)&WhHi[(kq*4+2)*512 + lane_off];
        short8 blo = *(const short8*)&WhLo[(kq*4+2)*512 + lane_off];
        racc = MFMA(ah2, bhi, racc); racc = MFMA(ah2, blo, racc);
      }
      {
        short8 bhi = *(const short8*)&WhHi[(kq*4+3)*512 + lane_off];
        short8 blo = *(const short8*)&WhLo[(kq*4+3)*512 + lane_off];
        racc = MFMA(ah3, bhi, racc); racc = MFMA(ah3, blo, racc);
      }
    }
    { // exchange partials: D layout col=lane&15, row=(lane>>4)*4+r
      const int bb = 16*m + hi16*4;
#pragma unroll
      for (int r4 = 0; r4 < 4; ++r4)
        exch[(kq*32 + bb + r4)*18 + lo16] = xacc[r4] + racc[r4];
    }
    __syncthreads();                       // S1: exch ready (joins both halves >= t)
    u32 pk_out = 0;
    if (tid < 128) { // gates: one (b,unit) per thread (R10 mapping)
      float zp=0.f, rp=0.f, xh=0.f, rh=0.f;
#pragma unroll
      for (int qd = 0; qd < 8; ++qd) {
        const float* e = &exch[(qd*32 + eb)*18];
        zp += e[eu_l];
        rp += e[4 + eu_l];
        xh += e[8 + eu_l];
        rh += e[12 + eu_l];
      }
      float z = 1.f/(1.f + __expf(-(zp + zb)));
      float r = 1.f/(1.f + __expf(-(rp + rbv)));
      float pre = xh + hxb + r*(rh + hrb);
      float ex = __expf(-2.f*fabsf(pre));
      float th = (1.f - ex)/(1.f + ex);
      float hh = copysignf(th, pre);
      float hn = z*harr[tid] + (1.f - z)*hh;
      harr[tid] = hn;
      pk_out = pack_f(hn);
      // h broadcast: bf16-hi only, two adjacent units packed per u32
      int pk16 = (int)(pk_out & 0xffffu);
      int prt  = __shfl_xor(pk16, 1);               // partner unit (eu_l^1)
      if ((tid & 1) == 0) {
        u32 pair = (u32)pk16 | ((u32)prt << 16);    // low = even unit
        ASTORE32(hbuf + nxt*16384 + eb*512 + wg*2 + (eu_l>>1), pair);
      }
    }
    asm volatile("s_waitcnt vmcnt(0)" ::: "memory");   // h stores acked at LLC
    __syncthreads();                                   // S2: whole WG's stores acked
    if (tid == 0)
      ASTORE32(flags + wg, t+1);
    if (tid < 128) {    // out_pack store moved off the publish path
      if (LAYER==0) {
        if ((t & 3) == 0)
          out_pack[((size_t)(t>>2)*32 + eb)*1024 + u0 + eu_l] = pk_out;
      } else {
        out_pack[((size_t)t*32 + eb)*1024 + u0 + eu_l] = pk_out;
      }
    }
  }
}

// ---------------- final dense head ----------------
__global__ __launch_bounds__(256, 1)
void dense_k(const u32* __restrict__ h2, const float* __restrict__ W,
             const float* __restrict__ bias, float* __restrict__ out){
  __shared__ float rows[32*1025];
  const int ts = blockIdx.x;
  const u32* src = h2 + (size_t)ts*32768;
  for (int i = threadIdx.x; i < 32768; i += 256){
    u32 p = src[i];
    rows[(i>>10)*1025 + (i&1023)] = bf2f(p & 0xffffu) + bf2f(p >> 16);
  }
  __syncthreads();
  const int b = threadIdx.x >> 3, cg = threadIdx.x & 7;
  float acc[6] = {0.f,0.f,0.f,0.f,0.f,0.f};
  for (int k = 0; k < 1024; ++k){
    float hv = rows[b*1025 + k];
    const float* wr = W + k*41;
#pragma unroll
    for (int j = 0; j < 6; ++j){ int c = cg + 8*j; if (c < 41) acc[j] += hv*wr[c]; }
  }
#pragma unroll
  for (int j = 0; j < 6; ++j){
    int c = cg + 8*j;
    if (c < 41) out[((size_t)b*250 + ts)*41 + c] = acc[j] + bias[c];
  }
}

// ---------------- launch ----------------
extern "C" void kernel_launch(void* const* d_in, const int* in_sizes, int n_in,
                              void* d_out, int out_size, void* d_ws, size_t ws_size,
                              hipStream_t stream) {
  const float* x      = (const float*)d_in[0];
  const float* conv_w = (const float*)d_in[1];
  const float* h0i    = (const float*)d_in[2];
  const float* w0x    = (const float*)d_in[3];
  const float* w0h    = (const float*)d_in[4];
  const float* b0     = (const float*)d_in[5];
  const float* w1x    = (const float*)d_in[6];
  const float* w1h    = (const float*)d_in[7];
  const float* b1     = (const float*)d_in[8];
  const float* dw     = (const float*)d_in[9];
  const float* db     = (const float*)d_in[10];
  float* outp = (float*)d_out;

  if (ws_size < WS_NEED) return;  // workspace too small: leave output poisoned

  char* ws = (char*)d_ws;
  u32* y_pack   = (u32*)(ws + OFF_Y);
  u32* out2     = (u32*)(ws + OFF_Y);      // reuse after y_pack is dead
  u32* sub_pack = (u32*)(ws + OFF_SUB);
  u16* w0x_hi = (u16*)(ws + OFF_W0XH); u16* w0x_lo = (u16*)(ws + OFF_W0XL);
  u16* w0h_hi = (u16*)(ws + OFF_W0HH); u16* w0h_lo = (u16*)(ws + OFF_W0HL);
  u16* w1x_hi = (u16*)(ws + OFF_W1XH); u16* w1x_lo = (u16*)(ws + OFF_W1XL);
  u16* w1h_hi = (u16*)(ws + OFF_W1HH); u16* w1h_lo = (u16*)(ws + OFF_W1HL);
  u32* hb0 = (u32*)(ws + OFF_HB0);
  u32* hb1 = (u32*)(ws + OFF_HB1);
  int* fl0 = (int*)(ws + OFF_FL0);
  int* fl1 = (int*)(ws + OFF_FL1);

  init_state<<<64, 512, 0, stream>>>(h0i, hb0, hb1, fl0, fl1);
  build_frags<<<2048, 256, 0, stream>>>(w0x, w0x_hi, w0x_lo, 256);
  build_frags<<<2048, 256, 0, stream>>>(w0h, w0h_hi, w0h_lo, 1024);
  build_frags<<<2048, 256, 0, stream>>>(w1x, w1x_hi, w1x_lo, 1024);
  build_frags<<<2048, 256, 0, stream>>>(w1h, w1h_hi, w1h_lo, 1024);
  conv_pack<<<4096, 256, 0, stream>>>(x, conv_w, y_pack);

  gru_persist<0><<<256, 1024, 0, stream>>>(y_pack, w0x_hi, w0x_lo, w0h_hi, w0h_lo,
                                           b0, hb0, fl0, sub_pack);
  gru_persist<1><<<256, 1024, 0, stream>>>(sub_pack, w1x_hi, w1x_lo, w1h_hi, w1h_lo,
                                           b1, hb1, fl1, out2);

  dense_k<<<250, 256, 0, stream>>>(out2, dw, db, outp);
}

// Round 13
// 5990.154 us; speedup vs baseline: 1.6306x; 1.0798x over previous
//
#include <hip/hip_runtime.h>

typedef unsigned int u32;
typedef unsigned long long u64;
typedef unsigned short u16;
typedef __attribute__((ext_vector_type(8))) short short8;
typedef __attribute__((ext_vector_type(4))) float f32x4;
typedef __attribute__((ext_vector_type(4))) unsigned int u32x4;

#define MFMA(a,b,c) __builtin_amdgcn_mfma_f32_16x16x32_bf16((a),(b),(c),0,0,0)
// Agent-scope (LLC) primitives — proven R3/R10/R12 path.
#define ALOAD32(p)    __hip_atomic_load((p), __ATOMIC_RELAXED, __HIP_MEMORY_SCOPE_AGENT)
#define ASTORE32(p,v) __hip_atomic_store((p),(v), __ATOMIC_RELAXED, __HIP_MEMORY_SCOPE_AGENT)

__device__ __forceinline__ float bf2f(u32 b){ union{u32 u; float f;} v; v.u = b<<16; return v.f; }
__device__ __forceinline__ u16 f2bf(float f){ union{float f; u32 u;} v; v.f = f; u32 u = v.u;
  return (u16)((u + 0x7fffu + ((u>>16)&1u)) >> 16); }
__device__ __forceinline__ u32 pack_f(float v){
  u16 hi = f2bf(v); u16 lo = f2bf(v - bf2f(hi)); return (u32)hi | ((u32)lo<<16); }

__device__ __forceinline__ void unpack8(uint4 a, uint4 b, short8& hi, short8& lo){
  u32 w[8] = {a.x,a.y,a.z,a.w,b.x,b.y,b.z,b.w};
#pragma unroll
  for (int j=0;j<8;++j){ hi[j] = (short)(w[j] & 0xffffu); lo[j] = (short)(w[j] >> 16); }
}
// one u32x4 (16 B) = 8 consecutive bf16 of the hi-only h plane
__device__ __forceinline__ void unpackh4(u32x4 a, short8& hi){
#pragma unroll
  for (int i=0;i<4;++i){ hi[2*i] = (short)(a[i] & 0xffffu); hi[2*i+1] = (short)(a[i] >> 16); }
}

// ---------------- workspace layout (bytes) — R11 footprint ----------------
constexpr size_t OFF_Y    = 0;            // u32[1000][32][256]; reused as out2 [250][32][1024]
constexpr size_t OFF_SUB  = 32768000;     // u32[250][32][1024]
constexpr size_t OFF_W0IH = 65536000;     // L0 weight image hi: 128*30720 u16 = 7,864,320 B
constexpr size_t OFF_W0IL = 73400320;     // L0 weight image lo
constexpr size_t OFF_W1XH = 81264640;     // L1 compact blobs (R3 builder)
constexpr size_t OFF_W1XL = 87556096;
constexpr size_t OFF_W1HH = 93847552;
constexpr size_t OFF_W1HL = 100139008;
constexpr size_t OFF_HB0  = 106430464;    // L0: u32[2 slot][2 grp][16][512] = 131072 B
constexpr size_t OFF_HB1  = 106692608;    // L1: u32[2 slot][32][512]        = 131072 B
constexpr size_t OFF_FL0  = 106954752;    // int[256] pad 1KB (grp0: 0..127, grp1: 128..255)
constexpr size_t OFF_FL1  = 106955776;
constexpr size_t WS_NEED  = 106956800;

// ---------------- L1 weight fragment builder (compact 12-col; R3-proven) ----------------
__global__ void build_frags(const float* __restrict__ W, u16* __restrict__ fhi,
                            u16* __restrict__ flo, int K){
  const int KT = K >> 8;
  size_t total = (size_t)K * 12 * 256;
  for (size_t i = (size_t)blockIdx.x*blockDim.x + threadIdx.x; i < total;
       i += (size_t)gridDim.x*blockDim.x){
    int j = (int)(i & 7); size_t r = i >> 3;
    int c = (int)(r % 12); r /= 12;
    int kseg = (int)(r & 3); r >>= 2;
    int kt = (int)(r % KT); r /= KT;
    int kq = (int)(r & 7); r >>= 3;
    int wg = (int)r;
    int k = kq*(K>>3) + kt*32 + kseg*8 + j;
    int col = (c>>2)*1024 + wg*4 + (c&3);
    float v = W[(size_t)k*3072 + col];
    u16 hi = f2bf(v);
    u16 lo = f2bf(v - bf2f(hi));
    fhi[i] = hi; flo[i] = lo;
  }
}

// ---------------- L0 weight image builder (8 units/image, 128 images) — R11-verified ----------------
// Per-image u16 (30720 elems/plane), regions (element offsets):
//   [0,4096)      ZRX : 8 blocks of 512; k=blk*32+kseg*8+j (<256);  [Wxz8|Wxr8]
//   [4096,20480)  ZRH : 32 blocks;       k=blk*32+kseg*8+j (<1024); [Whz8|Whr8]
//   [20480,24576) HHF : 8 blocks;        k (<256);                  [Wxh8|Whh8]
//   [24576,30720) HHC : 24 blocks*256;   k=256+blk*32+kseg*8+j;     [Whh8] (8 cols)
__global__ void build_w0img(const float* __restrict__ w0x, const float* __restrict__ w0h,
                            u16* __restrict__ imgH, u16* __restrict__ imgL){
  for (size_t i = (size_t)blockIdx.x*blockDim.x + threadIdx.x; i < 128ull*30720ull;
       i += (size_t)gridDim.x*blockDim.x){
    int wg = (int)(i / 30720), e = (int)(i % 30720);
    int k, col; const float* src;
    if (e < 4096){
      int blk=e>>9, r=e&511, kseg=r>>7, c=(r>>3)&15, j=r&7;
      k = blk*32 + kseg*8 + j;
      col = (c<8) ? (wg*8+c) : (1024 + wg*8 + c-8); src = w0x;
    } else if (e < 20480){
      int e2=e-4096, blk=e2>>9, r=e2&511, kseg=r>>7, c=(r>>3)&15, j=r&7;
      k = blk*32 + kseg*8 + j;
      col = (c<8) ? (wg*8+c) : (1024 + wg*8 + c-8); src = w0h;
    } else if (e < 24576){
      int e2=e-20480, blk=e2>>9, r=e2&511, kseg=r>>7, c=(r>>3)&15, j=r&7;
      k = blk*32 + kseg*8 + j;
      if (c < 8){ col = 2048 + wg*8 + c;     src = w0x; }
      else      { col = 2048 + wg*8 + c - 8; src = w0h; }
    } else {
      int e2=e-24576, blk=e2>>8, r=e2&255, kseg=r>>6, c=(r>>3)&7, j=r&7;
      k = 256 + blk*32 + kseg*8 + j;
      col = 2048 + wg*8 + c; src = w0h;
    }
    float v = src[(size_t)k*3072 + col];
    u16 hi = f2bf(v);
    imgH[i] = hi; imgL[i] = f2bf(v - bf2f(hi));
  }
}

// ---------------- init h0 + flags (bf16-hi pairs packed in u32) ----------------
__global__ void init_state(const float* __restrict__ h0, u32* hb0, u32* hb1,
                           int* f0, int* f1){
  int i = blockIdx.x*blockDim.x + threadIdx.x;
  if (i < 256){ f0[i]=0; f1[i]=0; }
  if (i < 16384){               // slot 0 (L0: both groups; L1: 32 rows). unit pair = i&511
    int p = i & 511;
    u32 v = (u32)f2bf(h0[2*p]) | ((u32)f2bf(h0[2*p+1]) << 16);
    hb0[i] = v;
    hb1[i] = 0u;
  }
}

// ---------------- conv + relu + pack ----------------
__global__ void conv_pack(const float* __restrict__ x, const float* __restrict__ cw,
                          u32* __restrict__ yp){
  for (size_t i = (size_t)blockIdx.x*blockDim.x + threadIdx.x; i < 8192000ull;
       i += (size_t)gridDim.x*blockDim.x){
    int f = (int)(i & 255); int b = (int)((i>>8)&31); int t = (int)(i>>13);
    const float* xb = x + ((size_t)b*1000 + t)*256 + f;
    float acc = xb[0]*cw[256+f];
    if (t > 0)   acc += xb[-256]*cw[f];
    if (t < 999) acc += xb[256]*cw[512+f];
    acc = fmaxf(acc, 0.0f);
    yp[i] = pack_f(acc);
  }
}

// ---------------- L0 sample-split persistent GRU: 256 WGs x 512 thr ----------------
// Group g=wg>>7 owns samples [g*16,g*16+16); local wid=wg&127 owns units
// [wid*8,wid*8+8). Per-WG h ingest = 32KB/step (group half only) -> aggregate
// 8 MB/step (2x less than R12). Waves: kq=wave (0..7) = K-eighth. Weight image
// + fragment math = R11-verified gru8; sync = R12-verified split-release +
// dwordx4 h loads + off-path out_pack. h plane: u32[2][2grp][16][512].
__global__ __launch_bounds__(512, 1)
void gru8s_persist(const u32* __restrict__ xin,
                   const u16* __restrict__ imgH, const u16* __restrict__ imgL,
                   const float* __restrict__ bias,
                   u32* hbuf, int* flags, u32* out_pack)
{
  __shared__ u16 WIMG[45056];        // hi[0,24576) + lo{ZRH,HHF}[24576,45056) = 90,112 B
  __shared__ float exch[128*33];     // 16,896 B
  __shared__ float harr[128];
  __shared__ int hready[32];         // [0]=units 0..511 ready step, [16]=units 512..1023

  const int tid  = threadIdx.x;
  const int wg   = blockIdx.x;
  const int g    = wg >> 7;
  const int wid  = wg & 127;
  const int lane = tid & 63;
  const int wave = tid >> 6;         // = kq (0..7)
  const int kq   = wave;
  const int lo16 = lane & 15, hi16 = lane >> 4;
  const int lane_off = hi16*128 + lo16*8;
  const int hsel = (kq >= 4) ? 16 : 0;

  { // stage weight image: hi 24576 elems = 6144 u64; lo [4096,24576) = 5120 u64
    const u64* sH = (const u64*)(imgH + (size_t)wid*30720);
    const u64* sL = (const u64*)(imgL + (size_t)wid*30720 + 4096);
    u64* dH = (u64*)WIMG;
    u64* dL = (u64*)(WIMG + 24576);
    for (int i = tid; i < 6144; i += 512) dH[i] = sH[i];
    for (int i = tid; i < 5120; i += 512) dL[i] = sL[i];
    if (tid < 32) hready[tid] = 0;
    if (tid < 128){   // fp32 h state: sample g*16+(tid>>3), unit wid*8+(tid&7)
      u16 hv = ((const u16*)hbuf)[g*16384 + (tid>>3)*1024 + wid*8 + (tid&7)];
      harr[tid] = bf2f((u32)hv);
    }
  }
  __syncthreads();

  // fragment pointers (R11-verified). LDS lo(img elem e) = WIMG[e+20480], e in [4096,24576).
  const u16* zrx_h  = &WIMG[kq*512 + lane_off];
  const u16* zrxg_l = imgL + (size_t)wid*30720 + kq*512 + lane_off;         // global
  const u16* zrh_h  = &WIMG[4096 + kq*2048 + lane_off];                     // +kt*512; lo=+20480
  const u16* hhx_h  = &WIMG[20480 + kq*512 + lane_off];                     // lo=+20480
  const bool hhLds  = (kq < 2);
  const u16* hhb_h; const u16* hhb_l; int hhstride;
  if (hhLds){
    hhb_h = &WIMG[20480 + kq*2048 + lane_off]; hhb_l = hhb_h + 20480; hhstride = 512;
  } else {
    size_t go = (size_t)wid*30720 + 24576 + (size_t)(kq-2)*1024 + hi16*64
              + ((lo16 >= 8) ? (lo16-8)*8 : 0);   // lo16<8 lanes: valid addr, result discarded
    hhb_h = imgH + go; hhb_l = imgL + go; hhstride = 256;
  }

  const int gs = tid >> 3, gu = tid & 7, eu = wid*8 + gu;   // local sample / unit
  const float zb  = bias[eu]        + bias[3072 + eu];
  const float rbv = bias[1024 + eu] + bias[4096 + eu];
  const float hxb = bias[2048 + eu];
  const float hrb = bias[5120 + eu];

  for (int t = 0; t < 1000; ++t) {
    const int cur = t & 1, nxt = cur ^ 1;
    f32x4 aZR = (f32x4){0.f,0.f,0.f,0.f};
    f32x4 aHX = (f32x4){0.f,0.f,0.f,0.f};
    f32x4 aHR = (f32x4){0.f,0.f,0.f,0.f};
    { // x-pass (h-independent; overlaps laggard flag propagation)
      const u32* xr = xin + ((size_t)t*32 + g*16 + lo16)*256 + kq*32 + hi16*8;
      uint4 a0 = *(const uint4*)xr;
      uint4 a1 = *(const uint4*)(xr + 4);
      short8 ahi, alo; unpack8(a0, a1, ahi, alo);
      short8 b1h = *(const short8*)zrx_h, b1l = *(const short8*)zrxg_l;
      short8 b2h = *(const short8*)hhx_h, b2l = *(const short8*)(hhx_h + 20480);
      aZR = MFMA(ahi,b1h,aZR); aZR = MFMA(alo,b1h,aZR); aZR = MFMA(ahi,b1l,aZR);
      aHX = MFMA(ahi,b2h,aHX); aHX = MFMA(alo,b2h,aHX); aHX = MFMA(ahi,b2l,aHX);
    }
    // split-release wait: wave0 polls group's flags[0..63] (units 0..511),
    // wave1 polls flags[64..127]; all waves spin on LDS word for their K-half.
    if (t > 0) {
      if (wave == 0) {
        int f0;
        do { f0 = ALOAD32(flags + g*128 + lane); } while (__all(f0 >= t) == 0);
        asm volatile("" ::: "memory");
        if (lane == 0) ((volatile int*)hready)[0] = t;
      } else if (wave == 1) {
        int f1;
        do { f1 = ALOAD32(flags + g*128 + 64 + lane); } while (__all(f1 >= t) == 0);
        asm volatile("" ::: "memory");
        if (lane == 0) ((volatile int*)hready)[16] = t;
      }
      while (((volatile int*)hready)[hsel] < t) { }
      asm volatile("" ::: "memory");   // pin h loads behind the release
    }
    { // h-pass: group's bf16-hi h rows; 4x dwordx4 LLC loads (line-perfect)
      const u32* hrow = hbuf + cur*16384 + g*8192 + lo16*512 + kq*64 + hi16*4;
      u32x4 qa, qb, qc, qd;
      asm volatile(
        "global_load_dwordx4 %0, %4, off sc0 sc1\n\t"
        "global_load_dwordx4 %1, %4, off offset:64 sc0 sc1\n\t"
        "global_load_dwordx4 %2, %4, off offset:128 sc0 sc1\n\t"
        "global_load_dwordx4 %3, %4, off offset:192 sc0 sc1\n\t"
        "s_waitcnt vmcnt(0)"
        : "=&v"(qa), "=&v"(qb), "=&v"(qc), "=&v"(qd)
        : "v"(hrow)
        : "memory");
      short8 ah0, ah1, ah2, ah3;
      unpackh4(qa, ah0); unpackh4(qb, ah1); unpackh4(qc, ah2); unpackh4(qd, ah3);
      {
        short8 b1h = *(const short8*)(zrh_h + 0*512);
        short8 b1l = *(const short8*)(zrh_h + 0*512 + 20480);
        short8 b2h = *(const short8*)(hhb_h + 0*hhstride);
        short8 b2l = *(const short8*)(hhb_l + 0*hhstride);
        aZR = MFMA(ah0,b1h,aZR); aZR = MFMA(ah0,b1l,aZR);
        aHR = MFMA(ah0,b2h,aHR); aHR = MFMA(ah0,b2l,aHR);
      }
      {
        short8 b1h = *(const short8*)(zrh_h + 1*512);
        short8 b1l = *(const short8*)(zrh_h + 1*512 + 20480);
        short8 b2h = *(const short8*)(hhb_h + 1*hhstride);
        short8 b2l = *(const short8*)(hhb_l + 1*hhstride);
        aZR = MFMA(ah1,b1h,aZR); aZR = MFMA(ah1,b1l,aZR);
        aHR = MFMA(ah1,b2h,aHR); aHR = MFMA(ah1,b2l,aHR);
      }
      {
        short8 b1h = *(const short8*)(zrh_h + 2*512);
        short8 b1l = *(const short8*)(zrh_h + 2*512 + 20480);
        short8 b2h = *(const short8*)(hhb_h + 2*hhstride);
        short8 b2l = *(const short8*)(hhb_l + 2*hhstride);
        aZR = MFMA(ah2,b1h,aZR); aZR = MFMA(ah2,b1l,aZR);
        aHR = MFMA(ah2,b2h,aHR); aHR = MFMA(ah2,b2l,aHR);
      }
      {
        short8 b1h = *(const short8*)(zrh_h + 3*512);
        short8 b1l = *(const short8*)(zrh_h + 3*512 + 20480);
        short8 b2h = *(const short8*)(hhb_h + 3*hhstride);
        short8 b2l = *(const short8*)(hhb_l + 3*hhstride);
        aZR = MFMA(ah3,b1h,aZR); aZR = MFMA(ah3,b1l,aZR);
        aHR = MFMA(ah3,b2h,aHR); aHR = MFMA(ah3,b2l,aHR);
      }
    }
    { // exchange: rows kq*16 + hi16*4 + r4; cols 0-15 = z|r, 16-23 = xh, 24-31 = rh
      const int bb = hi16*4;
#pragma unroll
      for (int r4 = 0; r4 < 4; ++r4){
        exch[(kq*16 + bb + r4)*33 + lo16]      = aZR[r4];
        exch[(kq*16 + bb + r4)*33 + 16 + lo16] = (lo16 < 8) ? aHX[r4] : aHR[r4];
      }
    }
    __syncthreads();                       // S1: exch ready (joins both K-halves >= t)
    u32 pk_out = 0;
    if (tid < 128) { // gates: one (local sample, unit) per thread
      float zp=0.f, rp=0.f, xh=0.f, rh=0.f;
#pragma unroll
      for (int k8 = 0; k8 < 8; ++k8){
        const float* e = &exch[(k8*16 + gs)*33];
        zp += e[gu]; rp += e[8+gu]; xh += e[16+gu]; rh += e[24+gu];
      }
      float z = 1.f/(1.f + __expf(-(zp + zb)));
      float r = 1.f/(1.f + __expf(-(rp + rbv)));
      float pre = xh + hxb + r*(rh + hrb);
      float ex = __expf(-2.f*fabsf(pre));
      float th = (1.f - ex)/(1.f + ex);
      float hh = copysignf(th, pre);
      float hn = z*harr[tid] + (1.f - z)*hh;
      harr[tid] = hn;
      pk_out = pack_f(hn);
      // h broadcast: bf16-hi, two adjacent units packed per u32, even lane stores
      int pk16 = (int)(pk_out & 0xffffu);
      int prt  = __shfl_xor(pk16, 1);               // partner unit (gu^1), same sample
      if ((tid & 1) == 0) {
        u32 pair = (u32)pk16 | ((u32)prt << 16);    // low = even unit
        ASTORE32(hbuf + nxt*16384 + g*8192 + gs*512 + wid*4 + (gu>>1), pair);
      }
    }
    asm volatile("s_waitcnt vmcnt(0)" ::: "memory");   // h stores acked at LLC
    __syncthreads();                                   // S2: whole WG's stores acked
    if (tid == 0)
      ASTORE32(flags + g*128 + wid, t+1);
    if (tid < 128) {    // sub_pack store off the publish path (packed {hi,lo})
      if ((t & 3) == 0)
        out_pack[((size_t)(t>>2)*32 + g*16 + gs)*1024 + eu] = pk_out;
    }
  }
}

// ---------------- L1 persistent GRU (R12-verified kernel, unchanged) ----------------
template<int LAYER>
__global__ __launch_bounds__(1024, 1)
void gru_persist(const u32* __restrict__ xin,
                 const u16* __restrict__ wxf_hi, const u16* __restrict__ wxf_lo,
                 const u16* __restrict__ whf_hi, const u16* __restrict__ whf_lo,
                 const float* __restrict__ bias,
                 u32* hbuf, int* flags, u32* out_pack)
{
  constexpr int T   = (LAYER==0) ? 1000 : 250;
  constexpr int KX  = (LAYER==0) ? 256 : 1024;
  constexpr int KTX = KX >> 8;
  __shared__ u16 WxHi[8*KTX*512], WxLo[8*KTX*512];
  __shared__ u16 WhHi[8*4*512],  WhLo[8*4*512];
  __shared__ float exch[8*32*18];
  __shared__ float harr[128];
  __shared__ int hready[32];

  const int tid  = threadIdx.x;
  const int wg   = blockIdx.x;
  const int lane = tid & 63;
  const int wave = tid >> 6;
  const int m    = wave & 1;
  const int kq   = wave >> 1;
  const int u0   = wg * 4;
  const int lo16 = lane & 15, hi16 = lane >> 4;
  const int lane_off = hi16*128 + lo16*8;
  const int hsel = (kq >= 4) ? 16 : 0;

  {
    for (int i = tid; i < 8*KTX*512/4; i += 1024){ ((u64*)WxHi)[i]=0; ((u64*)WxLo)[i]=0; }
    for (int i = tid; i < 8*4*512/4;  i += 1024){ ((u64*)WhHi)[i]=0; ((u64*)WhLo)[i]=0; }
    if (tid < 32) hready[tid] = 0;
  }
  __syncthreads();
  {
    const u16* bx_hi = wxf_hi + (size_t)wg*KX*12;
    const u16* bx_lo = wxf_lo + (size_t)wg*KX*12;
    const u16* bh_hi = whf_hi + (size_t)wg*1024*12;
    const u16* bh_lo = whf_lo + (size_t)wg*1024*12;
    for (int i = tid; i < 8*KTX*48; i += 1024){
      int c = i % 12; int r = i/12; int kseg = r & 3; r >>= 2;
      int kt = r % KTX; int kqq = r / KTX;
      int ldsoff = ((kqq*KTX+kt)*4+kseg)*128 + c*8;            // [z r xh 0]
      *(short8*)&WxHi[ldsoff] = *(const short8*)&bx_hi[(size_t)i*8];
      *(short8*)&WxLo[ldsoff] = *(const short8*)&bx_lo[(size_t)i*8];
    }
    for (int i = tid; i < 8*4*48; i += 1024){
      int c = i % 12; int r = i/12; int kseg = r & 3; r >>= 2;
      int kt = r & 3; int kqq = r >> 2;
      int cm = (c < 8) ? c : (c + 4);                          // [z r 0 rh]
      int ldsoff = ((kqq*4+kt)*4+kseg)*128 + cm*8;
      *(short8*)&WhHi[ldsoff] = *(const short8*)&bh_hi[(size_t)i*8];
      *(short8*)&WhLo[ldsoff] = *(const short8*)&bh_lo[(size_t)i*8];
    }
    if (tid < 128){
      u16 hv = ((const u16*)hbuf)[(tid>>2)*1024 + u0 + (tid&3)];
      harr[tid] = bf2f((u32)hv);
    }
  }
  __syncthreads();

  const int eb = tid >> 2, eu_l = tid & 3, eu = u0 + eu_l;
  const float zb  = bias[eu]        + bias[3072 + eu];
  const float rbv = bias[1024 + eu] + bias[4096 + eu];
  const float hxb = bias[2048 + eu];
  const float hrb = bias[5120 + eu];

  for (int t = 0; t < T; ++t) {
    const int cur = t & 1, nxt = cur ^ 1;
    f32x4 xacc = (f32x4){0.f,0.f,0.f,0.f};
    f32x4 racc = (f32x4){0.f,0.f,0.f,0.f};
    {
      const u32* xrow = xin + ((size_t)t*32 + 16*m + lo16)*KX + kq*(KX>>3) + hi16*8;
#pragma unroll
      for (int kt = 0; kt < KTX; ++kt) {
        uint4 a0 = *(const uint4*)(xrow + kt*32);
        uint4 a1 = *(const uint4*)(xrow + kt*32 + 4);
        short8 ahi, alo; unpack8(a0, a1, ahi, alo);
        short8 bhi = *(const short8*)&WxHi[(kq*KTX+kt)*512 + lane_off];
        short8 blo = *(const short8*)&WxLo[(kq*KTX+kt)*512 + lane_off];
        xacc = MFMA(ahi, bhi, xacc);
        xacc = MFMA(alo, bhi, xacc);
        xacc = MFMA(ahi, blo, xacc);
      }
    }
    if (t > 0) {
      if (wave == 0) {
        int f0, f1;
        do { f0 = ALOAD32(flags + lane); f1 = ALOAD32(flags + 64 + lane); }
        while (!__all(f0 >= t && f1 >= t));
        asm volatile("" ::: "memory");
        if (lane == 0) ((volatile int*)hready)[0] = t;
      } else if (wave == 1) {
        int f2, f3;
        do { f2 = ALOAD32(flags + 128 + lane); f3 = ALOAD32(flags + 192 + lane); }
        while (!__all(f2 >= t && f3 >= t));
        asm volatile("" ::: "memory");
        if (lane == 0) ((volatile int*)hready)[16] = t;
      }
      while (((volatile int*)hready)[hsel] < t) { }
      asm volatile("" ::: "memory");
    }
    {
      const u32* hrow = hbuf + cur*16384 + (16*m + lo16)*512 + kq*64 + hi16*4;
      u32x4 qa, qb, qc, qd;
      asm volatile(
        "global_load_dwordx4 %0, %4, off sc0 sc1\n\t"
        "global_load_dwordx4 %1, %4, off offset:64 sc0 sc1\n\t"
        "global_load_dwordx4 %2, %4, off offset:128 sc0 sc1\n\t"
        "global_load_dwordx4 %3, %4, off offset:192 sc0 sc1\n\t"
        "s_waitcnt vmcnt(0)"
        : "=&v"(qa), "=&v"(qb), "=&v"(qc), "=&v"(qd)
        : "v"(hrow)
        : "memory");
      short8 ah0, ah1, ah2, ah3;
      unpackh4(qa, ah0); unpackh4(qb, ah1); unpackh4(qc, ah2); unpackh4(qd, ah3);
      {
        short8 bhi = *(const short8*)&WhHi[(kq*4+0)*512 + lane_off];
        short8 blo = *(const short8*)&WhLo[(kq*4+0)*512 + lane_off];
        racc = MFMA(ah0, bhi, racc); racc = MFMA(ah0, blo, racc);
      }
      {
        short8 bhi = *(const short8*)&WhHi[(kq*4+1)*512 + lane_off];
        short8 blo = *(const short8*)&WhLo[(kq*4+1)*512 + lane_off];
        racc = MFMA(ah1, bhi, racc); racc = MFMA(ah1, blo, racc);
      }
      {
        short8 bhi = *(const short8*)&WhHi[(kq*4+2)*512 + lane_off];
        short8 blo = *(const short8*)&WhLo[(kq*4+2)*512 + lane_off];
        racc = MFMA(ah2, bhi, racc); racc = MFMA(ah2, blo, racc);
      }
      {
        short8 bhi = *(const short8*)&WhHi[(kq*4+3)*512 + lane_off];
        short8 blo = *(const short8*)&WhLo[(kq*4+3)*512 + lane_off];
        racc = MFMA(ah3, bhi, racc); racc = MFMA(ah3, blo, racc);
      }
    }
    {
      const int bb = 16*m + hi16*4;
#pragma unroll
      for (int r4 = 0; r4 < 4; ++r4)
        exch[(kq*32 + bb + r4)*18 + lo16] = xacc[r4] + racc[r4];
    }
    __syncthreads();
    u32 pk_out = 0;
    if (tid < 128) {
      float zp=0.f, rp=0.f, xh=0.f, rh=0.f;
#pragma unroll
      for (int qd = 0; qd < 8; ++qd) {
        const float* e = &exch[(qd*32 + eb)*18];
        zp += e[eu_l];
        rp += e[4 + eu_l];
        xh += e[8 + eu_l];
        rh += e[12 + eu_l];
      }
      float z = 1.f/(1.f + __expf(-(zp + zb)));
      float r = 1.f/(1.f + __expf(-(rp + rbv)));
      float pre = xh + hxb + r*(rh + hrb);
      float ex = __expf(-2.f*fabsf(pre));
      float th = (1.f - ex)/(1.f + ex);
      float hh = copysignf(th, pre);
      float hn = z*harr[tid] + (1.f - z)*hh;
      harr[tid] = hn;
      pk_out = pack_f(hn);
      int pk16 = (int)(pk_out & 0xffffu);
      int prt  = __shfl_xor(pk16, 1);
      if ((tid & 1) == 0) {
        u32 pair = (u32)pk16 | ((u32)prt << 16);
        ASTORE32(hbuf + nxt*16384 + eb*512 + wg*2 + (eu_l>>1), pair);
      }
    }
    asm volatile("s_waitcnt vmcnt(0)" ::: "memory");
    __syncthreads();
    if (tid == 0)
      ASTORE32(flags + wg, t+1);
    if (tid < 128) {
      if (LAYER==0) {
        if ((t & 3) == 0)
          out_pack[((size_t)(t>>2)*32 + eb)*1024 + u0 + eu_l] = pk_out;
      } else {
        out_pack[((size_t)t*32 + eb)*1024 + u0 + eu_l] = pk_out;
      }
    }
  }
}

// ---------------- final dense head ----------------
__global__ __launch_bounds__(256, 1)
void dense_k(const u32* __restrict__ h2, const float* __restrict__ W,
             const float* __restrict__ bias, float* __restrict__ out){
  __shared__ float rows[32*1025];
  const int ts = blockIdx.x;
  const u32* src = h2 + (size_t)ts*32768;
  for (int i = threadIdx.x; i < 32768; i += 256){
    u32 p = src[i];
    rows[(i>>10)*1025 + (i&1023)] = bf2f(p & 0xffffu) + bf2f(p >> 16);
  }
  __syncthreads();
  const int b = threadIdx.x >> 3, cg = threadIdx.x & 7;
  float acc[6] = {0.f,0.f,0.f,0.f,0.f,0.f};
  for (int k = 0; k < 1024; ++k){
    float hv = rows[b*1025 + k];
    const float* wr = W + k*41;
#pragma unroll
    for (int j = 0; j < 6; ++j){ int c = cg + 8*j; if (c < 41) acc[j] += hv*wr[c]; }
  }
#pragma unroll
  for (int j = 0; j < 6; ++j){
    int c = cg + 8*j;
    if (c < 41) out[((size_t)b*250 + ts)*41 + c] = acc[j] + bias[c];
  }
}

// ---------------- launch ----------------
extern "C" void kernel_launch(void* const* d_in, const int* in_sizes, int n_in,
                              void* d_out, int out_size, void* d_ws, size_t ws_size,
                              hipStream_t stream) {
  const float* x      = (const float*)d_in[0];
  const float* conv_w = (const float*)d_in[1];
  const float* h0i    = (const float*)d_in[2];
  const float* w0x    = (const float*)d_in[3];
  const float* w0h    = (const float*)d_in[4];
  const float* b0     = (const float*)d_in[5];
  const float* w1x    = (const float*)d_in[6];
  const float* w1h    = (const float*)d_in[7];
  const float* b1     = (const float*)d_in[8];
  const float* dw     = (const float*)d_in[9];
  const float* db     = (const float*)d_in[10];
  float* outp = (float*)d_out;

  if (ws_size < WS_NEED) return;  // workspace too small: leave output poisoned

  char* ws = (char*)d_ws;
  u32* y_pack   = (u32*)(ws + OFF_Y);
  u32* out2     = (u32*)(ws + OFF_Y);      // reuse after y_pack is dead
  u32* sub_pack = (u32*)(ws + OFF_SUB);
  u16* w0iH = (u16*)(ws + OFF_W0IH); u16* w0iL = (u16*)(ws + OFF_W0IL);
  u16* w1x_hi = (u16*)(ws + OFF_W1XH); u16* w1x_lo = (u16*)(ws + OFF_W1XL);
  u16* w1h_hi = (u16*)(ws + OFF_W1HH); u16* w1h_lo = (u16*)(ws + OFF_W1HL);
  u32* hb0 = (u32*)(ws + OFF_HB0);
  u32* hb1 = (u32*)(ws + OFF_HB1);
  int* fl0 = (int*)(ws + OFF_FL0);
  int* fl1 = (int*)(ws + OFF_FL1);

  init_state<<<64, 512, 0, stream>>>(h0i, hb0, hb1, fl0, fl1);
  build_w0img<<<2048, 256, 0, stream>>>(w0x, w0h, w0iH, w0iL);
  build_frags<<<2048, 256, 0, stream>>>(w1x, w1x_hi, w1x_lo, 1024);
  build_frags<<<2048, 256, 0, stream>>>(w1h, w1h_hi, w1h_lo, 1024);
  conv_pack<<<4096, 256, 0, stream>>>(x, conv_w, y_pack);

  gru8s_persist<<<256, 512, 0, stream>>>(y_pack, w0iH, w0iL, b0, hb0, fl0, sub_pack);
  gru_persist<1><<<256, 1024, 0, stream>>>(sub_pack, w1x_hi, w1x_lo, w1h_hi, w1h_lo,
                                           b1, hb1, fl1, out2);

  dense_k<<<250, 256, 0, stream>>>(out2, dw, db, outp);
}

// Round 14
// 5962.239 us; speedup vs baseline: 1.6382x; 1.0047x over previous
//
#include <hip/hip_runtime.h>

typedef unsigned int u32;
typedef unsigned long long u64;
typedef unsigned short u16;
typedef __attribute__((ext_vector_type(8))) short short8;
typedef __attribute__((ext_vector_type(4))) float f32x4;
typedef __attribute__((ext_vector_type(4))) unsigned int u32x4;

#define MFMA(a,b,c) __builtin_amdgcn_mfma_f32_16x16x32_bf16((a),(b),(c),0,0,0)
// Agent-scope (LLC) primitives — proven R3/R10/R12 path.
#define ALOAD32(p)    __hip_atomic_load((p), __ATOMIC_RELAXED, __HIP_MEMORY_SCOPE_AGENT)
#define ASTORE32(p,v) __hip_atomic_store((p),(v), __ATOMIC_RELAXED, __HIP_MEMORY_SCOPE_AGENT)

__device__ __forceinline__ float bf2f(u32 b){ union{u32 u; float f;} v; v.u = b<<16; return v.f; }
__device__ __forceinline__ u16 f2bf(float f){ union{float f; u32 u;} v; v.f = f; u32 u = v.u;
  return (u16)((u + 0x7fffu + ((u>>16)&1u)) >> 16); }
__device__ __forceinline__ u32 pack_f(float v){
  u16 hi = f2bf(v); u16 lo = f2bf(v - bf2f(hi)); return (u32)hi | ((u32)lo<<16); }

__device__ __forceinline__ void unpack8(uint4 a, uint4 b, short8& hi, short8& lo){
  u32 w[8] = {a.x,a.y,a.z,a.w,b.x,b.y,b.z,b.w};
#pragma unroll
  for (int j=0;j<8;++j){ hi[j] = (short)(w[j] & 0xffffu); lo[j] = (short)(w[j] >> 16); }
}
// one u32x4 (16 B) = 8 consecutive bf16 of the hi-only h plane
__device__ __forceinline__ void unpackh4(u32x4 a, short8& hi){
#pragma unroll
  for (int i=0;i<4;++i){ hi[2*i] = (short)(a[i] & 0xffffu); hi[2*i+1] = (short)(a[i] >> 16); }
}

// ---------------- workspace layout (bytes) — same footprint as R13 ----------------
constexpr size_t OFF_Y    = 0;            // u32[1000][32][256]; reused as out2 [250][32][1024]
constexpr size_t OFF_SUB  = 32768000;     // u32[250][32][1024]
constexpr size_t OFF_W0IH = 65536000;     // L0 image hi: 64 images x 61440 u16 = 7,864,320 B
constexpr size_t OFF_W0IL = 73400320;     // L0 image lo (same size)
constexpr size_t OFF_W1XH = 81264640;     // L1 compact blobs (R3 builder)
constexpr size_t OFF_W1XL = 87556096;
constexpr size_t OFF_W1HH = 93847552;
constexpr size_t OFF_W1HL = 100139008;
constexpr size_t OFF_HB0  = 106430464;    // L0: u32[2 slot][4 grp][8][512] = 131072 B
constexpr size_t OFF_HB1  = 106692608;    // L1: u32[2 slot][32][512]       = 131072 B
constexpr size_t OFF_FL0  = 106954752;    // int[256] pad 1KB (grp g: [g*64, g*64+64))
constexpr size_t OFF_FL1  = 106955776;
constexpr size_t WS_NEED  = 106956800;

// ---------------- L1 weight fragment builder (compact 12-col; R3-proven) ----------------
__global__ void build_frags(const float* __restrict__ W, u16* __restrict__ fhi,
                            u16* __restrict__ flo, int K){
  const int KT = K >> 8;
  size_t total = (size_t)K * 12 * 256;
  for (size_t i = (size_t)blockIdx.x*blockDim.x + threadIdx.x; i < total;
       i += (size_t)gridDim.x*blockDim.x){
    int j = (int)(i & 7); size_t r = i >> 3;
    int c = (int)(r % 12); r /= 12;
    int kseg = (int)(r & 3); r >>= 2;
    int kt = (int)(r % KT); r /= KT;
    int kq = (int)(r & 7); r >>= 3;
    int wg = (int)r;
    int k = kq*(K>>3) + kt*32 + kseg*8 + j;
    int col = (c>>2)*1024 + wg*4 + (c&3);
    float v = W[(size_t)k*3072 + col];
    u16 hi = f2bf(v);
    u16 lo = f2bf(v - bf2f(hi));
    fhi[i] = hi; flo[i] = lo;
  }
}

// ---------------- L0 weight image builder: 16 units/image, 64 images ----------------
// Per-image u16 plane = 61440 elems, SIX plain full-16-col regions (no fusion):
//   [0,4096)       ZX: Wxz16, K=256  (8 blks of 512)
//   [4096,8192)    RX: Wxr16, K=256
//   [8192,24576)   ZH: Whz16, K=1024 (32 blks)
//   [24576,40960)  RH: Whr16, K=1024
//   [40960,45056)  XH: Wxh16, K=256
//   [45056,61440)  HH: Whh16, K=1024
// block elem: r=e&511, kseg=r>>7, c=(r>>3)&15, j=r&7; k=blk*32+kseg*8+j
__global__ void build_w0img(const float* __restrict__ w0x, const float* __restrict__ w0h,
                            u16* __restrict__ imgH, u16* __restrict__ imgL){
  for (size_t i = (size_t)blockIdx.x*blockDim.x + threadIdx.x; i < 64ull*61440ull;
       i += (size_t)gridDim.x*blockDim.x){
    int wid = (int)(i / 61440), e = (int)(i % 61440);
    int e2, colbase; const float* src;
    if      (e < 4096) { e2 = e;         colbase = 0;    src = w0x; }
    else if (e < 8192) { e2 = e - 4096;  colbase = 1024; src = w0x; }
    else if (e < 24576){ e2 = e - 8192;  colbase = 0;    src = w0h; }
    else if (e < 40960){ e2 = e - 24576; colbase = 1024; src = w0h; }
    else if (e < 45056){ e2 = e - 40960; colbase = 2048; src = w0x; }
    else               { e2 = e - 45056; colbase = 2048; src = w0h; }
    int blk = e2 >> 9, r = e2 & 511;
    int kseg = r >> 7, c = (r >> 3) & 15, j = r & 7;
    int k = blk*32 + kseg*8 + j;
    int col = colbase + wid*16 + c;
    float v = src[(size_t)k*3072 + col];
    u16 hi = f2bf(v);
    imgH[i] = hi; imgL[i] = f2bf(v - bf2f(hi));
  }
}

// ---------------- init h0 + flags (bf16-hi pairs packed in u32) ----------------
__global__ void init_state(const float* __restrict__ h0, u32* hb0, u32* hb1,
                           int* f0, int* f1){
  int i = blockIdx.x*blockDim.x + threadIdx.x;
  if (i < 256){ f0[i]=0; f1[i]=0; }
  if (i < 16384){   // slot 0. L0: [4grp][8row][512]; L1: [32row][512] — both keyed by pair=i&511
    int p = i & 511;
    u32 v = (u32)f2bf(h0[2*p]) | ((u32)f2bf(h0[2*p+1]) << 16);
    hb0[i] = v;
    hb1[i] = 0u;
  }
}

// ---------------- conv + relu + pack ----------------
__global__ void conv_pack(const float* __restrict__ x, const float* __restrict__ cw,
                          u32* __restrict__ yp){
  for (size_t i = (size_t)blockIdx.x*blockDim.x + threadIdx.x; i < 8192000ull;
       i += (size_t)gridDim.x*blockDim.x){
    int f = (int)(i & 255); int b = (int)((i>>8)&31); int t = (int)(i>>13);
    const float* xb = x + ((size_t)b*1000 + t)*256 + f;
    float acc = xb[0]*cw[256+f];
    if (t > 0)   acc += xb[-256]*cw[f];
    if (t < 999) acc += xb[256]*cw[512+f];
    acc = fmaxf(acc, 0.0f);
    yp[i] = pack_f(acc);
  }
}

// ---------------- L0 4-group sample-split GRU: 256 WGs x 512 thr, 16 units/WG ----------------
// Group g=wg>>6 owns samples [g*8,g*8+8); wid=wg&63 owns units [wid*16,wid*16+16).
// Per-WG h ingest = 16 KB/step -> aggregate 4 MB/step (2x less than R13).
// MFMA A rows 8-15 duplicate rows 0-7 (coalesced; results discarded).
// hi weight plane (120 KB) in LDS; lo plane read from global (L2-resident).
// Sync = R12/R13-verified: wave0/1 K-half flag poll -> LDS release; S1/S2; pair-
// packed bf16-hi publish; off-path sub_pack store.
__global__ __launch_bounds__(512, 1)
void gru16_persist(const u32* __restrict__ xin,
                   const u16* __restrict__ imgH, const u16* __restrict__ imgL,
                   const float* __restrict__ bias,
                   u32* hbuf, int* flags, u32* out_pack)
{
  __shared__ u16 WIMG[61440];        // hi plane, 122,880 B
  __shared__ float exch[8*8*66];     // [kq][row8][66] = 16,896 B
  __shared__ float harr[128];        // 8 samples x 16 units
  __shared__ int hready[32];         // [0]=units 0..511, [16]=units 512..1023

  const int tid  = threadIdx.x;
  const int wg   = blockIdx.x;
  const int g    = wg >> 6;
  const int wid  = wg & 63;
  const int lane = tid & 63;
  const int wave = tid >> 6;         // = kq (0..7)
  const int kq   = wave;
  const int lo16 = lane & 15, hi16 = lane >> 4;
  const int lane_off = hi16*128 + lo16*8;
  const int hsel = (kq >= 4) ? 16 : 0;
  const int srow = lo16 & 7;         // sample row (rows 8-15 duplicate)

  { // stage hi plane: 61440 u16 = 15360 u64 (count = elems/4 — triple-checked)
    const u64* sH = (const u64*)(imgH + (size_t)wid*61440);
    u64* dH = (u64*)WIMG;
    for (int i = tid; i < 15360; i += 512) dH[i] = sH[i];
    if (tid < 32) hready[tid] = 0;
    if (tid < 128){   // fp32 h state: sample g*8+(tid>>4), unit wid*16+(tid&15)
      u16 hv = ((const u16*)hbuf)[g*8192 + (tid>>4)*1024 + wid*16 + (tid&15)];
      harr[tid] = bf2f((u32)hv);
    }
  }
  __syncthreads();

  // fragment pointers: LDS hi, global lo (same region offsets)
  const u16* gLo  = imgL + (size_t)wid*61440;
  const u16* zx_h = &WIMG[kq*512 + lane_off];          const u16* zx_l = gLo + kq*512 + lane_off;
  const u16* rx_h = &WIMG[4096 + kq*512 + lane_off];   const u16* rx_l = gLo + 4096 + kq*512 + lane_off;
  const u16* zh_h = &WIMG[8192 + kq*2048 + lane_off];  const u16* zh_l = gLo + 8192 + kq*2048 + lane_off;
  const u16* rh_h = &WIMG[24576 + kq*2048 + lane_off]; const u16* rh_l = gLo + 24576 + kq*2048 + lane_off;
  const u16* xh_h = &WIMG[40960 + kq*512 + lane_off];  const u16* xh_l = gLo + 40960 + kq*512 + lane_off;
  const u16* hh_h = &WIMG[45056 + kq*2048 + lane_off]; const u16* hh_l = gLo + 45056 + kq*2048 + lane_off;

  const int gs = tid >> 4, gu = tid & 15, eu = wid*16 + gu;   // gate: sample / unit
  const float zb  = bias[eu]        + bias[3072 + eu];
  const float rbv = bias[1024 + eu] + bias[4096 + eu];
  const float hxb = bias[2048 + eu];
  const float hrb = bias[5120 + eu];

  for (int t = 0; t < 1000; ++t) {
    const int cur = t & 1, nxt = cur ^ 1;
    f32x4 aZ  = (f32x4){0.f,0.f,0.f,0.f};
    f32x4 aR  = (f32x4){0.f,0.f,0.f,0.f};
    f32x4 aHX = (f32x4){0.f,0.f,0.f,0.f};
    f32x4 aHR = (f32x4){0.f,0.f,0.f,0.f};
    { // x-pass (h-independent; overlaps flag propagation). 1 kt per kq (K=256).
      const u32* xr = xin + ((size_t)t*32 + g*8 + srow)*256 + kq*32 + hi16*8;
      uint4 a0 = *(const uint4*)xr;
      uint4 a1 = *(const uint4*)(xr + 4);
      short8 ahi, alo; unpack8(a0, a1, ahi, alo);
      short8 bzh = *(const short8*)zx_h, bzl = *(const short8*)zx_l;
      short8 brh = *(const short8*)rx_h, brl = *(const short8*)rx_l;
      short8 bxh = *(const short8*)xh_h, bxl = *(const short8*)xh_l;
      aZ  = MFMA(ahi,bzh,aZ);  aZ  = MFMA(alo,bzh,aZ);  aZ  = MFMA(ahi,bzl,aZ);
      aR  = MFMA(ahi,brh,aR);  aR  = MFMA(alo,brh,aR);  aR  = MFMA(ahi,brl,aR);
      aHX = MFMA(ahi,bxh,aHX); aHX = MFMA(alo,bxh,aHX); aHX = MFMA(ahi,bxl,aHX);
    }
    // split-release wait: wave0 polls wids 0..31 (units 0..511), wave1 wids 32..63.
    if (t > 0) {
      if (wave == 0) {
        int f0;
        do { f0 = ALOAD32(flags + g*64 + (lane & 31)); } while (__all(f0 >= t) == 0);
        asm volatile("" ::: "memory");
        if (lane == 0) ((volatile int*)hready)[0] = t;
      } else if (wave == 1) {
        int f1;
        do { f1 = ALOAD32(flags + g*64 + 32 + (lane & 31)); } while (__all(f1 >= t) == 0);
        asm volatile("" ::: "memory");
        if (lane == 0) ((volatile int*)hready)[16] = t;
      }
      while (((volatile int*)hready)[hsel] < t) { }
      asm volatile("" ::: "memory");   // pin h loads behind the release
    }
    { // h-pass: group's 8 bf16-hi rows; 4x dwordx4 LLC loads (dup rows coalesce)
      const u32* hrow = hbuf + cur*16384 + g*4096 + srow*512 + kq*64 + hi16*4;
      u32x4 qa, qb, qc, qd;
      asm volatile(
        "global_load_dwordx4 %0, %4, off sc0 sc1\n\t"
        "global_load_dwordx4 %1, %4, off offset:64 sc0 sc1\n\t"
        "global_load_dwordx4 %2, %4, off offset:128 sc0 sc1\n\t"
        "global_load_dwordx4 %3, %4, off offset:192 sc0 sc1\n\t"
        "s_waitcnt vmcnt(0)"
        : "=&v"(qa), "=&v"(qb), "=&v"(qc), "=&v"(qd)
        : "v"(hrow)
        : "memory");
      short8 ah0, ah1, ah2, ah3;
      unpackh4(qa, ah0); unpackh4(qb, ah1); unpackh4(qc, ah2); unpackh4(qd, ah3);
#pragma unroll
      for (int kt = 0; kt < 4; ++kt){
        short8 ah = (kt==0)?ah0:(kt==1)?ah1:(kt==2)?ah2:ah3;
        short8 bzh = *(const short8*)(zh_h + kt*512), bzl = *(const short8*)(zh_l + kt*512);
        short8 brh = *(const short8*)(rh_h + kt*512), brl = *(const short8*)(rh_l + kt*512);
        short8 bhh = *(const short8*)(hh_h + kt*512), bhl = *(const short8*)(hh_l + kt*512);
        aZ  = MFMA(ah,bzh,aZ);  aZ  = MFMA(ah,bzl,aZ);
        aR  = MFMA(ah,brh,aR);  aR  = MFMA(ah,brl,aR);
        aHR = MFMA(ah,bhh,aHR); aHR = MFMA(ah,bhl,aHR);
      }
    }
    { // exchange: rows 0-7 only (hi16<2); cols: z[0,16) r[16,32) xh[32,48) rh[48,64)
      if (hi16 < 2) {
#pragma unroll
        for (int r4 = 0; r4 < 4; ++r4){
          float* e = &exch[(kq*8 + hi16*4 + r4)*66];
          e[lo16]      = aZ[r4];
          e[16 + lo16] = aR[r4];
          e[32 + lo16] = aHX[r4];
          e[48 + lo16] = aHR[r4];
        }
      }
    }
    __syncthreads();                       // S1: exch ready (joins both K-halves >= t)
    u32 pk_out = 0;
    if (tid < 128) { // gates: one (sample, unit) per thread
      float zp=0.f, rp=0.f, xh=0.f, rh=0.f;
#pragma unroll
      for (int k8 = 0; k8 < 8; ++k8){
        const float* e = &exch[(k8*8 + gs)*66];
        zp += e[gu]; rp += e[16+gu]; xh += e[32+gu]; rh += e[48+gu];
      }
      float z = 1.f/(1.f + __expf(-(zp + zb)));
      float r = 1.f/(1.f + __expf(-(rp + rbv)));
      float pre = xh + hxb + r*(rh + hrb);
      float ex = __expf(-2.f*fabsf(pre));
      float th = (1.f - ex)/(1.f + ex);
      float hh = copysignf(th, pre);
      float hn = z*harr[tid] + (1.f - z)*hh;
      harr[tid] = hn;
      pk_out = pack_f(hn);
      // h broadcast: bf16-hi, two adjacent units packed per u32, even lane stores
      int pk16 = (int)(pk_out & 0xffffu);
      int prt  = __shfl_xor(pk16, 1);               // partner unit (gu^1), same sample
      if ((tid & 1) == 0) {
        u32 pair = (u32)pk16 | ((u32)prt << 16);    // low = even unit
        ASTORE32(hbuf + nxt*16384 + g*4096 + gs*512 + wid*8 + (gu>>1), pair);
      }
    }
    asm volatile("s_waitcnt vmcnt(0)" ::: "memory");   // h stores acked at LLC
    __syncthreads();                                   // S2: whole WG's stores acked
    if (tid == 0)
      ASTORE32(flags + g*64 + wid, t+1);
    if (tid < 128) {    // sub_pack store off the publish path (packed {hi,lo})
      if ((t & 3) == 0)
        out_pack[((size_t)(t>>2)*32 + g*8 + gs)*1024 + eu] = pk_out;
    }
  }
}

// ---------------- L1 persistent GRU (R12/R13-verified kernel, unchanged) ----------------
template<int LAYER>
__global__ __launch_bounds__(1024, 1)
void gru_persist(const u32* __restrict__ xin,
                 const u16* __restrict__ wxf_hi, const u16* __restrict__ wxf_lo,
                 const u16* __restrict__ whf_hi, const u16* __restrict__ whf_lo,
                 const float* __restrict__ bias,
                 u32* hbuf, int* flags, u32* out_pack)
{
  constexpr int T   = (LAYER==0) ? 1000 : 250;
  constexpr int KX  = (LAYER==0) ? 256 : 1024;
  constexpr int KTX = KX >> 8;
  __shared__ u16 WxHi[8*KTX*512], WxLo[8*KTX*512];
  __shared__ u16 WhHi[8*4*512],  WhLo[8*4*512];
  __shared__ float exch[8*32*18];
  __shared__ float harr[128];
  __shared__ int hready[32];

  const int tid  = threadIdx.x;
  const int wg   = blockIdx.x;
  const int lane = tid & 63;
  const int wave = tid >> 6;
  const int m    = wave & 1;
  const int kq   = wave >> 1;
  const int u0   = wg * 4;
  const int lo16 = lane & 15, hi16 = lane >> 4;
  const int lane_off = hi16*128 + lo16*8;
  const int hsel = (kq >= 4) ? 16 : 0;

  {
    for (int i = tid; i < 8*KTX*512/4; i += 1024){ ((u64*)WxHi)[i]=0; ((u64*)WxLo)[i]=0; }
    for (int i = tid; i < 8*4*512/4;  i += 1024){ ((u64*)WhHi)[i]=0; ((u64*)WhLo)[i]=0; }
    if (tid < 32) hready[tid] = 0;
  }
  __syncthreads();
  {
    const u16* bx_hi = wxf_hi + (size_t)wg*KX*12;
    const u16* bx_lo = wxf_lo + (size_t)wg*KX*12;
    const u16* bh_hi = whf_hi + (size_t)wg*1024*12;
    const u16* bh_lo = whf_lo + (size_t)wg*1024*12;
    for (int i = tid; i < 8*KTX*48; i += 1024){
      int c = i % 12; int r = i/12; int kseg = r & 3; r >>= 2;
      int kt = r % KTX; int kqq = r / KTX;
      int ldsoff = ((kqq*KTX+kt)*4+kseg)*128 + c*8;            // [z r xh 0]
      *(short8*)&WxHi[ldsoff] = *(const short8*)&bx_hi[(size_t)i*8];
      *(short8*)&WxLo[ldsoff] = *(const short8*)&bx_lo[(size_t)i*8];
    }
    for (int i = tid; i < 8*4*48; i += 1024){
      int c = i % 12; int r = i/12; int kseg = r & 3; r >>= 2;
      int kt = r & 3; int kqq = r >> 2;
      int cm = (c < 8) ? c : (c + 4);                          // [z r 0 rh]
      int ldsoff = ((kqq*4+kt)*4+kseg)*128 + cm*8;
      *(short8*)&WhHi[ldsoff] = *(const short8*)&bh_hi[(size_t)i*8];
      *(short8*)&WhLo[ldsoff] = *(const short8*)&bh_lo[(size_t)i*8];
    }
    if (tid < 128){
      u16 hv = ((const u16*)hbuf)[(tid>>2)*1024 + u0 + (tid&3)];
      harr[tid] = bf2f((u32)hv);
    }
  }
  __syncthreads();

  const int eb = tid >> 2, eu_l = tid & 3, eu = u0 + eu_l;
  const float zb  = bias[eu]        + bias[3072 + eu];
  const float rbv = bias[1024 + eu] + bias[4096 + eu];
  const float hxb = bias[2048 + eu];
  const float hrb = bias[5120 + eu];

  for (int t = 0; t < T; ++t) {
    const int cur = t & 1, nxt = cur ^ 1;
    f32x4 xacc = (f32x4){0.f,0.f,0.f,0.f};
    f32x4 racc = (f32x4){0.f,0.f,0.f,0.f};
    {
      const u32* xrow = xin + ((size_t)t*32 + 16*m + lo16)*KX + kq*(KX>>3) + hi16*8;
#pragma unroll
      for (int kt = 0; kt < KTX; ++kt) {
        uint4 a0 = *(const uint4*)(xrow + kt*32);
        uint4 a1 = *(const uint4*)(xrow + kt*32 + 4);
        short8 ahi, alo; unpack8(a0, a1, ahi, alo);
        short8 bhi = *(const short8*)&WxHi[(kq*KTX+kt)*512 + lane_off];
        short8 blo = *(const short8*)&WxLo[(kq*KTX+kt)*512 + lane_off];
        xacc = MFMA(ahi, bhi, xacc);
        xacc = MFMA(alo, bhi, xacc);
        xacc = MFMA(ahi, blo, xacc);
      }
    }
    if (t > 0) {
      if (wave == 0) {
        int f0, f1;
        do { f0 = ALOAD32(flags + lane); f1 = ALOAD32(flags + 64 + lane); }
        while (!__all(f0 >= t && f1 >= t));
        asm volatile("" ::: "memory");
        if (lane == 0) ((volatile int*)hready)[0] = t;
      } else if (wave == 1) {
        int f2, f3;
        do { f2 = ALOAD32(flags + 128 + lane); f3 = ALOAD32(flags + 192 + lane); }
        while (!__all(f2 >= t && f3 >= t));
        asm volatile("" ::: "memory");
        if (lane == 0) ((volatile int*)hready)[16] = t;
      }
      while (((volatile int*)hready)[hsel] < t) { }
      asm volatile("" ::: "memory");
    }
    {
      const u32* hrow = hbuf + cur*16384 + (16*m + lo16)*512 + kq*64 + hi16*4;
      u32x4 qa, qb, qc, qd;
      asm volatile(
        "global_load_dwordx4 %0, %4, off sc0 sc1\n\t"
        "global_load_dwordx4 %1, %4, off offset:64 sc0 sc1\n\t"
        "global_load_dwordx4 %2, %4, off offset:128 sc0 sc1\n\t"
        "global_load_dwordx4 %3, %4, off offset:192 sc0 sc1\n\t"
        "s_waitcnt vmcnt(0)"
        : "=&v"(qa), "=&v"(qb), "=&v"(qc), "=&v"(qd)
        : "v"(hrow)
        : "memory");
      short8 ah0, ah1, ah2, ah3;
      unpackh4(qa, ah0); unpackh4(qb, ah1); unpackh4(qc, ah2); unpackh4(qd, ah3);
      {
        short8 bhi = *(const short8*)&WhHi[(kq*4+0)*512 + lane_off];
        short8 blo = *(const short8*)&WhLo[(kq*4+0)*512 + lane_off];
        racc = MFMA(ah0, bhi, racc); racc = MFMA(ah0, blo, racc);
      }
      {
        short8 bhi = *(const short8*)&WhHi[(kq*4+1)*512 + lane_off];
        short8 blo = *(const short8*)&WhLo[(kq*4+1)*512 + lane_off];
        racc = MFMA(ah1, bhi, racc); racc = MFMA(ah1, blo, racc);
      }
      {
        short8 bhi = *(const short8*)&WhHi[(kq*4+2)*512 + lane_off];
        short8 blo = *(const short8*)&WhLo[(kq*4+2)*512 + lane_off];
        racc = MFMA(ah2, bhi, racc); racc = MFMA(ah2, blo, racc);
      }
      {
        short8 bhi = *(const short8*)&WhHi[(kq*4+3)*512 + lane_off];
        short8 blo = *(const short8*)&WhLo[(kq*4+3)*512 + lane_off];
        racc = MFMA(ah3, bhi, racc); racc = MFMA(ah3, blo, racc);
      }
    }
    {
      const int bb = 16*m + hi16*4;
#pragma unroll
      for (int r4 = 0; r4 < 4; ++r4)
        exch[(kq*32 + bb + r4)*18 + lo16] = xacc[r4] + racc[r4];
    }
    __syncthreads();
    u32 pk_out = 0;
    if (tid < 128) {
      float zp=0.f, rp=0.f, xh=0.f, rh=0.f;
#pragma unroll
      for (int qd = 0; qd < 8; ++qd) {
        const float* e = &exch[(qd*32 + eb)*18];
        zp += e[eu_l];
        rp += e[4 + eu_l];
        xh += e[8 + eu_l];
        rh += e[12 + eu_l];
      }
      float z = 1.f/(1.f + __expf(-(zp + zb)));
      float r = 1.f/(1.f + __expf(-(rp + rbv)));
      float pre = xh + hxb + r*(rh + hrb);
      float ex = __expf(-2.f*fabsf(pre));
      float th = (1.f - ex)/(1.f + ex);
      float hh = copysignf(th, pre);
      float hn = z*harr[tid] + (1.f - z)*hh;
      harr[tid] = hn;
      pk_out = pack_f(hn);
      int pk16 = (int)(pk_out & 0xffffu);
      int prt  = __shfl_xor(pk16, 1);
      if ((tid & 1) == 0) {
        u32 pair = (u32)pk16 | ((u32)prt << 16);
        ASTORE32(hbuf + nxt*16384 + eb*512 + wg*2 + (eu_l>>1), pair);
      }
    }
    asm volatile("s_waitcnt vmcnt(0)" ::: "memory");
    __syncthreads();
    if (tid == 0)
      ASTORE32(flags + wg, t+1);
    if (tid < 128) {
      if (LAYER==0) {
        if ((t & 3) == 0)
          out_pack[((size_t)(t>>2)*32 + eb)*1024 + u0 + eu_l] = pk_out;
      } else {
        out_pack[((size_t)t*32 + eb)*1024 + u0 + eu_l] = pk_out;
      }
    }
  }
}

// ---------------- final dense head ----------------
__global__ __launch_bounds__(256, 1)
void dense_k(const u32* __restrict__ h2, const float* __restrict__ W,
             const float* __restrict__ bias, float* __restrict__ out){
  __shared__ float rows[32*1025];
  const int ts = blockIdx.x;
  const u32* src = h2 + (size_t)ts*32768;
  for (int i = threadIdx.x; i < 32768; i += 256){
    u32 p = src[i];
    rows[(i>>10)*1025 + (i&1023)] = bf2f(p & 0xffffu) + bf2f(p >> 16);
  }
  __syncthreads();
  const int b = threadIdx.x >> 3, cg = threadIdx.x & 7;
  float acc[6] = {0.f,0.f,0.f,0.f,0.f,0.f};
  for (int k = 0; k < 1024; ++k){
    float hv = rows[b*1025 + k];
    const float* wr = W + k*41;
#pragma unroll
    for (int j = 0; j < 6; ++j){ int c = cg + 8*j; if (c < 41) acc[j] += hv*wr[c]; }
  }
#pragma unroll
  for (int j = 0; j < 6; ++j){
    int c = cg + 8*j;
    if (c < 41) out[((size_t)b*250 + ts)*41 + c] = acc[j] + bias[c];
  }
}

// ---------------- launch ----------------
extern "C" void kernel_launch(void* const* d_in, const int* in_sizes, int n_in,
                              void* d_out, int out_size, void* d_ws, size_t ws_size,
                              hipStream_t stream) {
  const float* x      = (const float*)d_in[0];
  const float* conv_w = (const float*)d_in[1];
  const float* h0i    = (const float*)d_in[2];
  const float* w0x    = (const float*)d_in[3];
  const float* w0h    = (const float*)d_in[4];
  const float* b0     = (const float*)d_in[5];
  const float* w1x    = (const float*)d_in[6];
  const float* w1h    = (const float*)d_in[7];
  const float* b1     = (const float*)d_in[8];
  const float* dw     = (const float*)d_in[9];
  const float* db     = (const float*)d_in[10];
  float* outp = (float*)d_out;

  if (ws_size < WS_NEED) return;  // workspace too small: leave output poisoned

  char* ws = (char*)d_ws;
  u32* y_pack   = (u32*)(ws + OFF_Y);
  u32* out2     = (u32*)(ws + OFF_Y);      // reuse after y_pack is dead
  u32* sub_pack = (u32*)(ws + OFF_SUB);
  u16* w0iH = (u16*)(ws + OFF_W0IH); u16* w0iL = (u16*)(ws + OFF_W0IL);
  u16* w1x_hi = (u16*)(ws + OFF_W1XH); u16* w1x_lo = (u16*)(ws + OFF_W1XL);
  u16* w1h_hi = (u16*)(ws + OFF_W1HH); u16* w1h_lo = (u16*)(ws + OFF_W1HL);
  u32* hb0 = (u32*)(ws + OFF_HB0);
  u32* hb1 = (u32*)(ws + OFF_HB1);
  int* fl0 = (int*)(ws + OFF_FL0);
  int* fl1 = (int*)(ws + OFF_FL1);

  init_state<<<64, 512, 0, stream>>>(h0i, hb0, hb1, fl0, fl1);
  build_w0img<<<2048, 256, 0, stream>>>(w0x, w0h, w0iH, w0iL);
  build_frags<<<2048, 256, 0, stream>>>(w1x, w1x_hi, w1x_lo, 1024);
  build_frags<<<2048, 256, 0, stream>>>(w1h, w1h_hi, w1h_lo, 1024);
  conv_pack<<<4096, 256, 0, stream>>>(x, conv_w, y_pack);

  gru16_persist<<<256, 512, 0, stream>>>(y_pack, w0iH, w0iL, b0, hb0, fl0, sub_pack);
  gru_persist<1><<<256, 1024, 0, stream>>>(sub_pack, w1x_hi, w1x_lo, w1h_hi, w1h_lo,
                                           b1, hb1, fl1, out2);

  dense_k<<<250, 256, 0, stream>>>(out2, dw, db, outp);
}

// Round 15
// 5418.898 us; speedup vs baseline: 1.8025x; 1.1003x over previous
//
#include <hip/hip_runtime.h>

typedef unsigned int u32;
typedef unsigned long long u64;
typedef unsigned short u16;
typedef __attribute__((ext_vector_type(8))) short short8;
typedef __attribute__((ext_vector_type(4))) float f32x4;
typedef __attribute__((ext_vector_type(4))) unsigned int u32x4;

#define MFMA(a,b,c) __builtin_amdgcn_mfma_f32_16x16x32_bf16((a),(b),(c),0,0,0)
// Agent-scope (LLC) primitives — proven R3/R10/R12 path.
#define ALOAD32(p)    __hip_atomic_load((p), __ATOMIC_RELAXED, __HIP_MEMORY_SCOPE_AGENT)
#define ASTORE32(p,v) __hip_atomic_store((p),(v), __ATOMIC_RELAXED, __HIP_MEMORY_SCOPE_AGENT)

__device__ __forceinline__ float bf2f(u32 b){ union{u32 u; float f;} v; v.u = b<<16; return v.f; }
__device__ __forceinline__ u16 f2bf(float f){ union{float f; u32 u;} v; v.f = f; u32 u = v.u;
  return (u16)((u + 0x7fffu + ((u>>16)&1u)) >> 16); }
__device__ __forceinline__ u32 pack_f(float v){
  u16 hi = f2bf(v); u16 lo = f2bf(v - bf2f(hi)); return (u32)hi | ((u32)lo<<16); }

__device__ __forceinline__ void unpack8(uint4 a, uint4 b, short8& hi, short8& lo){
  u32 w[8] = {a.x,a.y,a.z,a.w,b.x,b.y,b.z,b.w};
#pragma unroll
  for (int j=0;j<8;++j){ hi[j] = (short)(w[j] & 0xffffu); lo[j] = (short)(w[j] >> 16); }
}
// one u32x4 (16 B) = 8 consecutive bf16 of the hi-only h plane
__device__ __forceinline__ void unpackh4(u32x4 a, short8& hi){
#pragma unroll
  for (int i=0;i<4;++i){ hi[2*i] = (short)(a[i] & 0xffffu); hi[2*i+1] = (short)(a[i] >> 16); }
}

// ---------------- workspace layout (bytes) ----------------
constexpr size_t OFF_Y    = 0;            // u32[1000][32][256]; reused as out2 [250][32][1024]
constexpr size_t OFF_SUB  = 32768000;     // u32[250][32][1024]
constexpr size_t OFF_W0IH = 65536000;     // L0 image hi: 64 x 61440 u16 = 7,864,320 B
constexpr size_t OFF_W0IL = 73400320;     // L0 image lo
constexpr size_t OFF_W1IH = 81264640;     // L1 image hi: 128 x 49152 u16 = 12,582,912 B
constexpr size_t OFF_W1IL = 93847552;     // L1 image lo
constexpr size_t OFF_HB0  = 106430464;    // L0: u32[2 slot][4 grp][8][512] = 131072 B
constexpr size_t OFF_HB1  = 106692608;    // L1: u32[2 slot][2 grp][16][512] = 131072 B
constexpr size_t OFF_FL0  = 106954752;    // int[256] pad 1KB (grp g: [g*64,g*64+64))
constexpr size_t OFF_FL1  = 106955776;    // int[256] (grp g: [g*128,g*128+128))
constexpr size_t WS_NEED  = 106956800;

// ---------------- L0 weight image builder: 16 units/image, 64 images (R14-verified) ----------------
// Per-image u16 plane = 61440 elems, SIX plain full-16-col regions:
//   [0,4096) ZX | [4096,8192) RX | [8192,24576) ZH | [24576,40960) RH
//   [40960,45056) XH | [45056,61440) HH
// block elem: r=e&511, kseg=r>>7, c=(r>>3)&15, j=r&7; k=blk*32+kseg*8+j
__global__ void build_w0img(const float* __restrict__ w0x, const float* __restrict__ w0h,
                            u16* __restrict__ imgH, u16* __restrict__ imgL){
  for (size_t i = (size_t)blockIdx.x*blockDim.x + threadIdx.x; i < 64ull*61440ull;
       i += (size_t)gridDim.x*blockDim.x){
    int wid = (int)(i / 61440), e = (int)(i % 61440);
    int e2, colbase; const float* src;
    if      (e < 4096) { e2 = e;         colbase = 0;    src = w0x; }
    else if (e < 8192) { e2 = e - 4096;  colbase = 1024; src = w0x; }
    else if (e < 24576){ e2 = e - 8192;  colbase = 0;    src = w0h; }
    else if (e < 40960){ e2 = e - 24576; colbase = 1024; src = w0h; }
    else if (e < 45056){ e2 = e - 40960; colbase = 2048; src = w0x; }
    else               { e2 = e - 45056; colbase = 2048; src = w0h; }
    int blk = e2 >> 9, r = e2 & 511;
    int kseg = r >> 7, c = (r >> 3) & 15, j = r & 7;
    int k = blk*32 + kseg*8 + j;
    int col = colbase + wid*16 + c;
    float v = src[(size_t)k*3072 + col];
    u16 hi = f2bf(v);
    imgH[i] = hi; imgL[i] = f2bf(v - bf2f(hi));
  }
}

// ---------------- L1 weight image builder: 8 units/image, 128 images, FUSED 16-col tiles ----------------
// Per-image u16 plane = 49152 elems, THREE K=1024 regions of 16384:
//   [0,16384)      ZRX: [Wxz8|Wxr8]   (src w1x)
//   [16384,32768)  ZRH: [Whz8|Whr8]   (src w1h)
//   [32768,49152)  XHH: [Wxh8|Whh8]   (c<8: w1x, c>=8: w1h)
// block elem: rr=e2&511, kseg=rr>>7, c=(rr>>3)&15, j=rr&7; k=blk*32+kseg*8+j
__global__ void build_w1img(const float* __restrict__ w1x, const float* __restrict__ w1h,
                            u16* __restrict__ imgH, u16* __restrict__ imgL){
  for (size_t i = (size_t)blockIdx.x*blockDim.x + threadIdx.x; i < 128ull*49152ull;
       i += (size_t)gridDim.x*blockDim.x){
    int wid = (int)(i / 49152), e = (int)(i % 49152);
    int rg = e >> 14, e2 = e & 16383;
    int blk = e2 >> 9, rr = e2 & 511;
    int kseg = rr >> 7, c = (rr >> 3) & 15, j = rr & 7;
    int k = blk*32 + kseg*8 + j;
    const float* src; int col;
    if (rg == 0){ src = w1x; col = (c<8) ? (wid*8+c) : (1024 + wid*8 + c-8); }
    else if (rg == 1){ src = w1h; col = (c<8) ? (wid*8+c) : (1024 + wid*8 + c-8); }
    else { col = 2048 + wid*8 + ((c<8) ? c : c-8); src = (c<8) ? w1x : w1h; }
    float v = src[(size_t)k*3072 + col];
    u16 hi = f2bf(v);
    imgH[i] = hi; imgL[i] = f2bf(v - bf2f(hi));
  }
}

// ---------------- init h0 + flags (bf16-hi pairs packed in u32) ----------------
__global__ void init_state(const float* __restrict__ h0, u32* hb0, u32* hb1,
                           int* f0, int* f1){
  int i = blockIdx.x*blockDim.x + threadIdx.x;
  if (i < 256){ f0[i]=0; f1[i]=0; }
  if (i < 16384){   // slot 0. L0: [4grp][8row][512]; L1: [2grp][16row][512] — pair = i&511
    int p = i & 511;
    u32 v = (u32)f2bf(h0[2*p]) | ((u32)f2bf(h0[2*p+1]) << 16);
    hb0[i] = v;
    hb1[i] = 0u;
  }
}

// ---------------- conv + relu + pack ----------------
__global__ void conv_pack(const float* __restrict__ x, const float* __restrict__ cw,
                          u32* __restrict__ yp){
  for (size_t i = (size_t)blockIdx.x*blockDim.x + threadIdx.x; i < 8192000ull;
       i += (size_t)gridDim.x*blockDim.x){
    int f = (int)(i & 255); int b = (int)((i>>8)&31); int t = (int)(i>>13);
    const float* xb = x + ((size_t)b*1000 + t)*256 + f;
    float acc = xb[0]*cw[256+f];
    if (t > 0)   acc += xb[-256]*cw[f];
    if (t < 999) acc += xb[256]*cw[512+f];
    acc = fmaxf(acc, 0.0f);
    yp[i] = pack_f(acc);
  }
}

// ---------------- L0 4-group sample-split GRU (R14-verified, byte-identical) ----------------
__global__ __launch_bounds__(512, 1)
void gru16_persist(const u32* __restrict__ xin,
                   const u16* __restrict__ imgH, const u16* __restrict__ imgL,
                   const float* __restrict__ bias,
                   u32* hbuf, int* flags, u32* out_pack)
{
  __shared__ u16 WIMG[61440];        // hi plane, 122,880 B
  __shared__ float exch[8*8*66];     // 16,896 B
  __shared__ float harr[128];
  __shared__ int hready[32];

  const int tid  = threadIdx.x;
  const int wg   = blockIdx.x;
  const int g    = wg >> 6;
  const int wid  = wg & 63;
  const int lane = tid & 63;
  const int wave = tid >> 6;
  const int kq   = wave;
  const int lo16 = lane & 15, hi16 = lane >> 4;
  const int lane_off = hi16*128 + lo16*8;
  const int hsel = (kq >= 4) ? 16 : 0;
  const int srow = lo16 & 7;

  {
    const u64* sH = (const u64*)(imgH + (size_t)wid*61440);
    u64* dH = (u64*)WIMG;
    for (int i = tid; i < 15360; i += 512) dH[i] = sH[i];
    if (tid < 32) hready[tid] = 0;
    if (tid < 128){
      u16 hv = ((const u16*)hbuf)[g*8192 + (tid>>4)*1024 + wid*16 + (tid&15)];
      harr[tid] = bf2f((u32)hv);
    }
  }
  __syncthreads();

  const u16* gLo  = imgL + (size_t)wid*61440;
  const u16* zx_h = &WIMG[kq*512 + lane_off];          const u16* zx_l = gLo + kq*512 + lane_off;
  const u16* rx_h = &WIMG[4096 + kq*512 + lane_off];   const u16* rx_l = gLo + 4096 + kq*512 + lane_off;
  const u16* zh_h = &WIMG[8192 + kq*2048 + lane_off];  const u16* zh_l = gLo + 8192 + kq*2048 + lane_off;
  const u16* rh_h = &WIMG[24576 + kq*2048 + lane_off]; const u16* rh_l = gLo + 24576 + kq*2048 + lane_off;
  const u16* xh_h = &WIMG[40960 + kq*512 + lane_off];  const u16* xh_l = gLo + 40960 + kq*512 + lane_off;
  const u16* hh_h = &WIMG[45056 + kq*2048 + lane_off]; const u16* hh_l = gLo + 45056 + kq*2048 + lane_off;

  const int gs = tid >> 4, gu = tid & 15, eu = wid*16 + gu;
  const float zb  = bias[eu]        + bias[3072 + eu];
  const float rbv = bias[1024 + eu] + bias[4096 + eu];
  const float hxb = bias[2048 + eu];
  const float hrb = bias[5120 + eu];

  for (int t = 0; t < 1000; ++t) {
    const int cur = t & 1, nxt = cur ^ 1;
    f32x4 aZ  = (f32x4){0.f,0.f,0.f,0.f};
    f32x4 aR  = (f32x4){0.f,0.f,0.f,0.f};
    f32x4 aHX = (f32x4){0.f,0.f,0.f,0.f};
    f32x4 aHR = (f32x4){0.f,0.f,0.f,0.f};
    {
      const u32* xr = xin + ((size_t)t*32 + g*8 + srow)*256 + kq*32 + hi16*8;
      uint4 a0 = *(const uint4*)xr;
      uint4 a1 = *(const uint4*)(xr + 4);
      short8 ahi, alo; unpack8(a0, a1, ahi, alo);
      short8 bzh = *(const short8*)zx_h, bzl = *(const short8*)zx_l;
      short8 brh = *(const short8*)rx_h, brl = *(const short8*)rx_l;
      short8 bxh = *(const short8*)xh_h, bxl = *(const short8*)xh_l;
      aZ  = MFMA(ahi,bzh,aZ);  aZ  = MFMA(alo,bzh,aZ);  aZ  = MFMA(ahi,bzl,aZ);
      aR  = MFMA(ahi,brh,aR);  aR  = MFMA(alo,brh,aR);  aR  = MFMA(ahi,brl,aR);
      aHX = MFMA(ahi,bxh,aHX); aHX = MFMA(alo,bxh,aHX); aHX = MFMA(ahi,bxl,aHX);
    }
    if (t > 0) {
      if (wave == 0) {
        int f0;
        do { f0 = ALOAD32(flags + g*64 + (lane & 31)); } while (__all(f0 >= t) == 0);
        asm volatile("" ::: "memory");
        if (lane == 0) ((volatile int*)hready)[0] = t;
      } else if (wave == 1) {
        int f1;
        do { f1 = ALOAD32(flags + g*64 + 32 + (lane & 31)); } while (__all(f1 >= t) == 0);
        asm volatile("" ::: "memory");
        if (lane == 0) ((volatile int*)hready)[16] = t;
      }
      while (((volatile int*)hready)[hsel] < t) { }
      asm volatile("" ::: "memory");
    }
    {
      const u32* hrow = hbuf + cur*16384 + g*4096 + srow*512 + kq*64 + hi16*4;
      u32x4 qa, qb, qc, qd;
      asm volatile(
        "global_load_dwordx4 %0, %4, off sc0 sc1\n\t"
        "global_load_dwordx4 %1, %4, off offset:64 sc0 sc1\n\t"
        "global_load_dwordx4 %2, %4, off offset:128 sc0 sc1\n\t"
        "global_load_dwordx4 %3, %4, off offset:192 sc0 sc1\n\t"
        "s_waitcnt vmcnt(0)"
        : "=&v"(qa), "=&v"(qb), "=&v"(qc), "=&v"(qd)
        : "v"(hrow)
        : "memory");
      short8 ah0, ah1, ah2, ah3;
      unpackh4(qa, ah0); unpackh4(qb, ah1); unpackh4(qc, ah2); unpackh4(qd, ah3);
#pragma unroll
      for (int kt = 0; kt < 4; ++kt){
        short8 ah = (kt==0)?ah0:(kt==1)?ah1:(kt==2)?ah2:ah3;
        short8 bzh = *(const short8*)(zh_h + kt*512), bzl = *(const short8*)(zh_l + kt*512);
        short8 brh = *(const short8*)(rh_h + kt*512), brl = *(const short8*)(rh_l + kt*512);
        short8 bhh = *(const short8*)(hh_h + kt*512), bhl = *(const short8*)(hh_l + kt*512);
        aZ  = MFMA(ah,bzh,aZ);  aZ  = MFMA(ah,bzl,aZ);
        aR  = MFMA(ah,brh,aR);  aR  = MFMA(ah,brl,aR);
        aHR = MFMA(ah,bhh,aHR); aHR = MFMA(ah,bhl,aHR);
      }
    }
    {
      if (hi16 < 2) {
#pragma unroll
        for (int r4 = 0; r4 < 4; ++r4){
          float* e = &exch[(kq*8 + hi16*4 + r4)*66];
          e[lo16]      = aZ[r4];
          e[16 + lo16] = aR[r4];
          e[32 + lo16] = aHX[r4];
          e[48 + lo16] = aHR[r4];
        }
      }
    }
    __syncthreads();
    u32 pk_out = 0;
    if (tid < 128) {
      float zp=0.f, rp=0.f, xh=0.f, rh=0.f;
#pragma unroll
      for (int k8 = 0; k8 < 8; ++k8){
        const float* e = &exch[(k8*8 + gs)*66];
        zp += e[gu]; rp += e[16+gu]; xh += e[32+gu]; rh += e[48+gu];
      }
      float z = 1.f/(1.f + __expf(-(zp + zb)));
      float r = 1.f/(1.f + __expf(-(rp + rbv)));
      float pre = xh + hxb + r*(rh + hrb);
      float ex = __expf(-2.f*fabsf(pre));
      float th = (1.f - ex)/(1.f + ex);
      float hh = copysignf(th, pre);
      float hn = z*harr[tid] + (1.f - z)*hh;
      harr[tid] = hn;
      pk_out = pack_f(hn);
      int pk16 = (int)(pk_out & 0xffffu);
      int prt  = __shfl_xor(pk16, 1);
      if ((tid & 1) == 0) {
        u32 pair = (u32)pk16 | ((u32)prt << 16);
        ASTORE32(hbuf + nxt*16384 + g*4096 + gs*512 + wid*8 + (gu>>1), pair);
      }
    }
    asm volatile("s_waitcnt vmcnt(0)" ::: "memory");
    __syncthreads();
    if (tid == 0)
      ASTORE32(flags + g*64 + wid, t+1);
    if (tid < 128) {
      if ((t & 3) == 0)
        out_pack[((size_t)(t>>2)*32 + g*8 + gs)*1024 + eu] = pk_out;
    }
  }
}

// ---------------- L1 2-group sample-split GRU: 256 WGs x 512 thr, 8 units/WG ----------------
// Group g=wg>>7 owns samples [g*16,g*16+16); wid=wg&127 owns units [wid*8,wid*8+8).
// Fused K=1024 tiles: ZRX=[Wxz8|Wxr8], ZRH=[Whz8|Whr8], XHH=[Wxh8|Whh8] (x-pass keeps
// left 8 cols, h-pass right 8). hi plane (96KB) LDS; lo plane global/L2.
// Per-WG h ingest = 32 KB/step -> aggregate 8 MB/step (2x less than R14's L1).
// Sync / publish / flags verbatim from R13-verified gru8s.
__global__ __launch_bounds__(512, 1)
void gru8L1_persist(const u32* __restrict__ xin,
                    const u16* __restrict__ imgH, const u16* __restrict__ imgL,
                    const float* __restrict__ bias,
                    u32* hbuf, int* flags, u32* out_pack)
{
  __shared__ u16 WIMG[49152];        // hi plane, 98,304 B
  __shared__ float exch[8*16*33];    // 16,896 B
  __shared__ float harr[128];        // 16 samples x 8 units
  __shared__ int hready[32];         // [0]=units 0..511 (wids 0-63), [16]=512..1023

  const int tid  = threadIdx.x;
  const int wg   = blockIdx.x;
  const int g    = wg >> 7;
  const int wid  = wg & 127;
  const int lane = tid & 63;
  const int wave = tid >> 6;         // = kq (0..7), K-eighth of 1024
  const int kq   = wave;
  const int lo16 = lane & 15, hi16 = lane >> 4;
  const int lane_off = hi16*128 + lo16*8;
  const int hsel = (kq >= 4) ? 16 : 0;

  { // stage hi plane: 49152 u16 = 12288 u64 (count = elems/4)
    const u64* sH = (const u64*)(imgH + (size_t)wid*49152);
    u64* dH = (u64*)WIMG;
    for (int i = tid; i < 12288; i += 512) dH[i] = sH[i];
    if (tid < 32) hready[tid] = 0;
    if (tid < 128){   // fp32 h state: sample g*16+(tid>>3), unit wid*8+(tid&7) — slot0 zeros
      u16 hv = ((const u16*)hbuf)[g*16384 + (tid>>3)*1024 + wid*8 + (tid&7)];
      harr[tid] = bf2f((u32)hv);
    }
  }
  __syncthreads();

  // fragment pointers: LDS hi, global lo. kq covers blks [kq*4, kq*4+4).
  const u16* gLo   = imgL + (size_t)wid*49152;
  const u16* zrx_h = &WIMG[kq*2048 + lane_off];          const u16* zrx_l = gLo + kq*2048 + lane_off;
  const u16* zrh_h = &WIMG[16384 + kq*2048 + lane_off];  const u16* zrh_l = gLo + 16384 + kq*2048 + lane_off;
  const u16* xhh_h = &WIMG[32768 + kq*2048 + lane_off];  const u16* xhh_l = gLo + 32768 + kq*2048 + lane_off;

  const int gs = tid >> 3, gu = tid & 7, eu = wid*8 + gu;   // gate: sample(0..15) / unit
  const float zb  = bias[eu]        + bias[3072 + eu];
  const float rbv = bias[1024 + eu] + bias[4096 + eu];
  const float hxb = bias[2048 + eu];
  const float hrb = bias[5120 + eu];

  for (int t = 0; t < 250; ++t) {
    const int cur = t & 1, nxt = cur ^ 1;
    f32x4 aZR = (f32x4){0.f,0.f,0.f,0.f};
    f32x4 aXH = (f32x4){0.f,0.f,0.f,0.f};
    f32x4 aHR = (f32x4){0.f,0.f,0.f,0.f};
    { // x-pass (h-independent): sub_pack rows g*16+lo16, k in [kq*128, kq*128+128)
      const u32* xrow = xin + ((size_t)t*32 + g*16 + lo16)*1024 + kq*128 + hi16*8;
#pragma unroll
      for (int kt = 0; kt < 4; ++kt) {
        uint4 a0 = *(const uint4*)(xrow + kt*32);
        uint4 a1 = *(const uint4*)(xrow + kt*32 + 4);
        short8 ahi, alo; unpack8(a0, a1, ahi, alo);
        short8 bzh = *(const short8*)(zrx_h + kt*512), bzl = *(const short8*)(zrx_l + kt*512);
        short8 bxh = *(const short8*)(xhh_h + kt*512), bxl = *(const short8*)(xhh_l + kt*512);
        aZR = MFMA(ahi,bzh,aZR); aZR = MFMA(alo,bzh,aZR); aZR = MFMA(ahi,bzl,aZR);
        aXH = MFMA(ahi,bxh,aXH); aXH = MFMA(alo,bxh,aXH); aXH = MFMA(ahi,bxl,aXH);
      }
    }
    // split-release wait: wave0 polls group's wids 0..63, wave1 wids 64..127.
    if (t > 0) {
      if (wave == 0) {
        int f0;
        do { f0 = ALOAD32(flags + g*128 + lane); } while (__all(f0 >= t) == 0);
        asm volatile("" ::: "memory");
        if (lane == 0) ((volatile int*)hready)[0] = t;
      } else if (wave == 1) {
        int f1;
        do { f1 = ALOAD32(flags + g*128 + 64 + lane); } while (__all(f1 >= t) == 0);
        asm volatile("" ::: "memory");
        if (lane == 0) ((volatile int*)hready)[16] = t;
      }
      while (((volatile int*)hready)[hsel] < t) { }
      asm volatile("" ::: "memory");   // pin h loads behind the release
    }
    { // h-pass: group's 16 bf16-hi rows; 4x dwordx4 LLC loads
      const u32* hrow = hbuf + cur*16384 + g*8192 + lo16*512 + kq*64 + hi16*4;
      u32x4 qa, qb, qc, qd;
      asm volatile(
        "global_load_dwordx4 %0, %4, off sc0 sc1\n\t"
        "global_load_dwordx4 %1, %4, off offset:64 sc0 sc1\n\t"
        "global_load_dwordx4 %2, %4, off offset:128 sc0 sc1\n\t"
        "global_load_dwordx4 %3, %4, off offset:192 sc0 sc1\n\t"
        "s_waitcnt vmcnt(0)"
        : "=&v"(qa), "=&v"(qb), "=&v"(qc), "=&v"(qd)
        : "v"(hrow)
        : "memory");
      short8 ah0, ah1, ah2, ah3;
      unpackh4(qa, ah0); unpackh4(qb, ah1); unpackh4(qc, ah2); unpackh4(qd, ah3);
#pragma unroll
      for (int kt = 0; kt < 4; ++kt){
        short8 ah = (kt==0)?ah0:(kt==1)?ah1:(kt==2)?ah2:ah3;
        short8 bzh = *(const short8*)(zrh_h + kt*512), bzl = *(const short8*)(zrh_l + kt*512);
        short8 bhh = *(const short8*)(xhh_h + kt*512), bhl = *(const short8*)(xhh_l + kt*512);
        aZR = MFMA(ah,bzh,aZR); aZR = MFMA(ah,bzl,aZR);
        aHR = MFMA(ah,bhh,aHR); aHR = MFMA(ah,bhl,aHR);
      }
    }
    { // exchange: 16 rows (samples); cols 0-15 = z|r, 16-23 = xh (lo16<8), 24-31 = rh
#pragma unroll
      for (int r4 = 0; r4 < 4; ++r4){
        float* e = &exch[(kq*16 + hi16*4 + r4)*33];
        e[lo16]      = aZR[r4];
        e[16 + lo16] = (lo16 < 8) ? aXH[r4] : aHR[r4];
      }
    }
    __syncthreads();                       // S1: exch ready (all flags >= t joined)
    u32 pk_out = 0;
    if (tid < 128) { // gates: one (sample, unit) per thread
      float zp=0.f, rp=0.f, xh=0.f, rh=0.f;
#pragma unroll
      for (int k8 = 0; k8 < 8; ++k8){
        const float* e = &exch[(k8*16 + gs)*33];
        zp += e[gu]; rp += e[8+gu]; xh += e[16+gu]; rh += e[24+gu];
      }
      float z = 1.f/(1.f + __expf(-(zp + zb)));
      float r = 1.f/(1.f + __expf(-(rp + rbv)));
      float pre = xh + hxb + r*(rh + hrb);
      float ex = __expf(-2.f*fabsf(pre));
      float th = (1.f - ex)/(1.f + ex);
      float hh = copysignf(th, pre);
      float hn = z*harr[tid] + (1.f - z)*hh;
      harr[tid] = hn;
      pk_out = pack_f(hn);
      // h broadcast: bf16-hi, two adjacent units per u32, even lane stores
      int pk16 = (int)(pk_out & 0xffffu);
      int prt  = __shfl_xor(pk16, 1);
      if ((tid & 1) == 0) {
        u32 pair = (u32)pk16 | ((u32)prt << 16);
        ASTORE32(hbuf + nxt*16384 + g*8192 + gs*512 + wid*4 + (gu>>1), pair);
      }
    }
    asm volatile("s_waitcnt vmcnt(0)" ::: "memory");   // h stores acked at LLC
    __syncthreads();                                   // S2
    if (tid == 0)
      ASTORE32(flags + g*128 + wid, t+1);
    if (tid < 128) {    // out2 store off the publish path (packed {hi,lo})
      out_pack[((size_t)t*32 + g*16 + gs)*1024 + eu] = pk_out;
    }
  }
}

// ---------------- final dense head ----------------
__global__ __launch_bounds__(256, 1)
void dense_k(const u32* __restrict__ h2, const float* __restrict__ W,
             const float* __restrict__ bias, float* __restrict__ out){
  __shared__ float rows[32*1025];
  const int ts = blockIdx.x;
  const u32* src = h2 + (size_t)ts*32768;
  for (int i = threadIdx.x; i < 32768; i += 256){
    u32 p = src[i];
    rows[(i>>10)*1025 + (i&1023)] = bf2f(p & 0xffffu) + bf2f(p >> 16);
  }
  __syncthreads();
  const int b = threadIdx.x >> 3, cg = threadIdx.x & 7;
  float acc[6] = {0.f,0.f,0.f,0.f,0.f,0.f};
  for (int k = 0; k < 1024; ++k){
    float hv = rows[b*1025 + k];
    const float* wr = W + k*41;
#pragma unroll
    for (int j = 0; j < 6; ++j){ int c = cg + 8*j; if (c < 41) acc[j] += hv*wr[c]; }
  }
#pragma unroll
  for (int j = 0; j < 6; ++j){
    int c = cg + 8*j;
    if (c < 41) out[((size_t)b*250 + ts)*41 + c] = acc[j] + bias[c];
  }
}

// ---------------- launch ----------------
extern "C" void kernel_launch(void* const* d_in, const int* in_sizes, int n_in,
                              void* d_out, int out_size, void* d_ws, size_t ws_size,
                              hipStream_t stream) {
  const float* x      = (const float*)d_in[0];
  const float* conv_w = (const float*)d_in[1];
  const float* h0i    = (const float*)d_in[2];
  const float* w0x    = (const float*)d_in[3];
  const float* w0h    = (const float*)d_in[4];
  const float* b0     = (const float*)d_in[5];
  const float* w1x    = (const float*)d_in[6];
  const float* w1h    = (const float*)d_in[7];
  const float* b1     = (const float*)d_in[8];
  const float* dw     = (const float*)d_in[9];
  const float* db     = (const float*)d_in[10];
  float* outp = (float*)d_out;

  if (ws_size < WS_NEED) return;  // workspace too small: leave output poisoned

  char* ws = (char*)d_ws;
  u32* y_pack   = (u32*)(ws + OFF_Y);
  u32* out2     = (u32*)(ws + OFF_Y);      // reuse after y_pack is dead
  u32* sub_pack = (u32*)(ws + OFF_SUB);
  u16* w0iH = (u16*)(ws + OFF_W0IH); u16* w0iL = (u16*)(ws + OFF_W0IL);
  u16* w1iH = (u16*)(ws + OFF_W1IH); u16* w1iL = (u16*)(ws + OFF_W1IL);
  u32* hb0 = (u32*)(ws + OFF_HB0);
  u32* hb1 = (u32*)(ws + OFF_HB1);
  int* fl0 = (int*)(ws + OFF_FL0);
  int* fl1 = (int*)(ws + OFF_FL1);

  init_state<<<64, 512, 0, stream>>>(h0i, hb0, hb1, fl0, fl1);
  build_w0img<<<2048, 256, 0, stream>>>(w0x, w0h, w0iH, w0iL);
  build_w1img<<<2048, 256, 0, stream>>>(w1x, w1h, w1iH, w1iL);
  conv_pack<<<4096, 256, 0, stream>>>(x, conv_w, y_pack);

  gru16_persist<<<256, 512, 0, stream>>>(y_pack, w0iH, w0iL, b0, hb0, fl0, sub_pack);
  gru8L1_persist<<<256, 512, 0, stream>>>(sub_pack, w1iH, w1iL, b1, hb1, fl1, out2);

  dense_k<<<250, 256, 0, stream>>>(out2, dw, db, outp);
}